// Round 5
// baseline (645.934 us; speedup 1.0000x reference)
//
#include <hip/hip_runtime.h>

// BiLSTM on MI355X.
//  - l1_scan / l2f_scan: 12-wave blocks (3 waves/SIMD) for latency overlap in
//    the serial per-step chain; gates fully in-register via permuted MFMA
//    weight packing (jj = tile*4 + q); 7-trans fused LSTM cell; one raw
//    barrier per step (lgkmcnt only — global loads/stores stay in flight).
//  - l2f: x-fragments streamed from global (prefetch 1 step ahead, register-
//    consumed, OR-merged into kt3), h double-buffered in LDS.
//  - l2b: backward scan's last output = single step from zero state.
//  - bias folded as an extra K-column against a constant-1.0 B row.

typedef unsigned short u16;
typedef unsigned int u32;
typedef float f32x4 __attribute__((ext_vector_type(4)));
typedef _Float16 f16x8 __attribute__((ext_vector_type(8)));
typedef short s16x8 __attribute__((ext_vector_type(8)));

#if __has_builtin(__builtin_amdgcn_mfma_f32_16x16x32_f16)
#define USE_F16 1
#else
#define USE_F16 0
#endif

#define B1 1024
#define TT 128

__device__ __forceinline__ u16 to_h(float x) {
#if USE_F16
    _Float16 h = (_Float16)x;
    return __builtin_bit_cast(u16, h);
#else
    u32 u = __builtin_bit_cast(u32, x);
    u32 r = u + 0x7FFFu + ((u >> 16) & 1u);
    return (u16)(r >> 16);
#endif
}
__device__ __forceinline__ float from_h(u16 s) {
#if USE_F16
    return (float)__builtin_bit_cast(_Float16, s);
#else
    u32 u = ((u32)s) << 16;
    return __builtin_bit_cast(float, u);
#endif
}

__device__ __forceinline__ f32x4 mfma16(uint4 a, uint4 b, f32x4 c) {
#if USE_F16
    return __builtin_amdgcn_mfma_f32_16x16x32_f16(
        __builtin_bit_cast(f16x8, a), __builtin_bit_cast(f16x8, b), c, 0, 0, 0);
#else
    return __builtin_amdgcn_mfma_f32_16x16x32_bf16(
        __builtin_bit_cast(s16x8, a), __builtin_bit_cast(s16x8, b), c, 0, 0, 0);
#endif
}

#define LOG2E 1.4426950408889634f
__device__ __forceinline__ float sigm(float x) {
    return __builtin_amdgcn_rcpf(1.f + __builtin_amdgcn_exp2f(-LOG2E * x));
}
__device__ __forceinline__ float tanh_(float x) {
    return 1.f - 2.f * __builtin_amdgcn_rcpf(1.f + __builtin_amdgcn_exp2f(2.f * LOG2E * x));
}
__device__ __forceinline__ float clampf(float x, float k) {
    return fminf(fmaxf(x, -k), k);
}

// Fused LSTM cell: c' = sigm(f)*c + sigm(i)*tanh(g); h = sigm(o)*tanh(c').
// Shared-denominator form: 5 exp2 + 2 rcp (vs 10 trans naive). Clamps keep
// all products finite in f32; |rel err| ~1e-7.
__device__ __forceinline__ float lstm_cell(float ig, float fg, float gg, float og,
                                           float& c)
{
    float ei = __builtin_amdgcn_exp2f(-LOG2E * clampf(ig, 25.f));
    float ef = __builtin_amdgcn_exp2f(-LOG2E * clampf(fg, 25.f));
    float eg = __builtin_amdgcn_exp2f(2.f * LOG2E * clampf(gg, 15.f));
    float P   = (1.f + ei) * (eg + 1.f);
    float num = fmaf(c, P, (eg - 1.f) * (1.f + ef));
    float cn  = num * __builtin_amdgcn_rcpf((1.f + ef) * P);
    c = cn;
    float eo = __builtin_amdgcn_exp2f(-LOG2E * clampf(og, 25.f));
    float ec = __builtin_amdgcn_exp2f(2.f * LOG2E * clampf(cn, 15.f));
    return (ec - 1.f) * __builtin_amdgcn_rcpf((1.f + eo) * (ec + 1.f));
}

// Raw workgroup barrier: waits only LDS ops (lgkmcnt); global loads/stores
// stay in flight across it (compiler inserts counted vmcnt at register uses).
__device__ __forceinline__ void wg_barrier_lds() {
    __builtin_amdgcn_sched_barrier(0);
    asm volatile("s_waitcnt lgkmcnt(0)" ::: "memory");
    __builtin_amdgcn_s_barrier();
    __builtin_amdgcn_sched_barrier(0);
}

// ---------------------------------------------------------------------------
// Weight packing [Wih | Whh | bias-col | 0] into MFMA A-fragments, permuted:
// tile row m = q*4 + tau maps to original weight row tau*GR + (tile*4 + q).
// Consumer thread (lane q*16+b) owning tile gets gates (i,f,g,o) of group
// jj = tile*4+q in acc[0..3] -> nonlinearity fully in-register.
__device__ __forceinline__ void prep_frag_body(
    const float* __restrict__ Wih, const float* __restrict__ Whh,
    const float* __restrict__ bias, uint4* __restrict__ dst,
    int GR, int KT, int x_off, int x_len, int h_off, int h_len, int bias_k,
    int bid, int l)
{
    int tile = bid / KT, kt = bid - tile * KT;
    int ml = l & 15;
    int qq = ml >> 2, tau = ml & 3;
    int jj = tile * 4 + qq;
    bool valid = jj < GR;
    int row = tau * GR + jj;
    u32 dw[4];
    #pragma unroll
    for (int d = 0; d < 4; ++d) {
        u16 hh[2];
        #pragma unroll
        for (int s = 0; s < 2; ++s) {
            int j = d * 2 + s;
            int k = kt * 32 + (l >> 4) * 8 + j;
            float val = 0.f;
            if (valid) {
                if (k >= x_off && k < x_off + x_len) val = Wih[row * x_len + (k - x_off)];
                else if (k >= h_off && k < h_off + h_len) val = Whh[row * h_len + (k - h_off)];
                else if (k == bias_k) val = bias[row];
            }
            hh[s] = to_h(val);
        }
        dw[d] = (u32)hh[0] | ((u32)hh[1] << 16);
    }
    uint4 o; o.x = dw[0]; o.y = dw[1]; o.z = dw[2]; o.w = dw[3];
    dst[bid * 64 + l] = o;
}

__global__ void prep_all(const float* __restrict__ W1ihF, const float* __restrict__ W1hhF,
                         const float* __restrict__ b1F,
                         const float* __restrict__ W1ihB, const float* __restrict__ W1hhB,
                         const float* __restrict__ b1B,
                         const float* __restrict__ W2ihF, const float* __restrict__ W2hhF,
                         const float* __restrict__ b2F, const float* __restrict__ W2ihB,
                         uint4* __restrict__ frag1f, uint4* __restrict__ frag1b,
                         uint4* __restrict__ frag2f, float* __restrict__ WtT)
{
    int bid = blockIdx.x;
    int l = threadIdx.x;
    if (bid < 32)
        prep_frag_body(W1ihF, W1hhF, b1F, frag1f, 50, 2, 0, 1, 1, 50, 63, bid, l);
    else if (bid < 64)
        prep_frag_body(W1ihB, W1hhB, b1B, frag1b, 50, 2, 0, 1, 1, 50, 63, bid - 32, l);
    else if (bid < 384)
        prep_frag_body(W2ihF, W2hhF, b2F, frag2f, 150, 8, 0, 100, 100, 150, 255, bid - 64, l);
    else {
        int idx = (bid - 384) * 64 + l;          // WtT[k][g] = W2ihB[g][k]
        if (idx < 60000) {
            int k = idx / 600, g = idx - k * 600;
            WtT[idx] = W2ihB[g * 100 + k];
        }
    }
}

// ---------------------------------------------------------------------------
// Layer 1: K=64 (x k=0, h k=1..50, bias k=63). 768 thr = 12 waves, 2 tile
// slots/wave (tile = w + 12p, valid <= 12), groups jj = tile*4 + q (< 50).
// out1f layout: u16 fragment tensor [t][blk16][ktx(4)][lane(64)][e(8)].
__global__ __launch_bounds__(768) void l1_scan(
    const float* __restrict__ x, const uint4* __restrict__ fragF,
    const uint4* __restrict__ fragB, u16* __restrict__ out1f)
{
    const int tid = threadIdx.x;
    const int lane = tid & 63;
    const int w = tid >> 6;
    const int q = lane >> 4;
    const int b = lane & 15;
    const int blk = blockIdx.x;
    const int dir = blockIdx.y;
    const uint4* frag = dir ? fragB : fragF;

    __shared__ u16 v[2][1024];        // [buf][kt(2)*64 lanes*8 e]
    __shared__ float x_s[128][17];    // padded: conflict-free col reads

    uint4 af[2][2];
    #pragma unroll
    for (int i = 0; i < 2; ++i) {
        int tile = w + 12 * i;
        if (tile <= 12)
            #pragma unroll
            for (int kt = 0; kt < 2; ++kt)
                af[i][kt] = frag[(tile * 2 + kt) * 64 + lane];
    }

    const int b0 = blk * 16;
    for (int idx = tid; idx < 1024; idx += 768) ((u32*)v)[idx] = 0u;
    for (int idx = tid; idx < 2048; idx += 768) {
        int bb = idx >> 7, t = idx & 127;
        x_s[t][bb] = x[(size_t)(b0 + bb) * TT + t];
    }
    __syncthreads();                  // zero-init complete before special slots
    const u16 oneh = to_h(1.0f);
    if (tid < 16) {
        v[0][(112 + tid) * 8 + 7] = oneh;             // bias row k=63, both bufs
        v[1][(112 + tid) * 8 + 7] = oneh;
        v[0][tid * 8] = to_h(x[(size_t)(b0 + tid) * TT + (dir ? TT - 1 : 0)]);
    }
    int vslot[2]; size_t eb[2];
    #pragma unroll
    for (int p = 0; p < 2; ++p) {
        int jj = (w + 12 * p) * 4 + q;
        int k = 1 + jj;
        vslot[p] = ((k >> 5) * 64 + ((k & 31) >> 3) * 16 + b) * 8 + (k & 7);
        int k2 = dir * 50 + (jj < 50 ? jj : 0);
        eb[p] = (((size_t)blk * 4 + (k2 >> 5)) * 64 + ((k2 & 31) >> 3) * 16 + b) * 8 + (k2 & 7);
    }
    float c[2] = {0.f, 0.f};
    __syncthreads();

#define L1_STEP(T, CUR) { \
    uint4 bf0 = *(const uint4*)&v[CUR][lane * 8]; \
    uint4 bf1 = *(const uint4*)&v[CUR][(64 + lane) * 8]; \
    f32x4 acc[2]; \
    _Pragma("unroll") for (int i = 0; i < 2; ++i) acc[i] = (f32x4){0.f, 0.f, 0.f, 0.f}; \
    _Pragma("unroll") for (int i = 0; i < 2; ++i) { \
        if (w + 12 * i <= 12) { \
            acc[i] = mfma16(af[i][0], bf0, acc[i]); \
            acc[i] = mfma16(af[i][1], bf1, acc[i]); \
        } \
    } \
    const int tt = dir ? 127 - (T) : (T); \
    _Pragma("unroll") for (int p = 0; p < 2; ++p) { \
        int jj = (w + 12 * p) * 4 + q; \
        if (jj < 50) { \
            float hn = lstm_cell(acc[p][0], acc[p][1], acc[p][2], acc[p][3], c[p]); \
            u16 hb = to_h(hn); \
            out1f[eb[p] + (size_t)tt * 131072] = hb; \
            v[1 - (CUR)][vslot[p]] = hb; \
        } \
    } \
    if (tid < 16 && (T) < 127) \
        v[1 - (CUR)][tid * 8] = to_h(x_s[dir ? 126 - (T) : (T) + 1][tid]); \
    wg_barrier_lds(); }

    for (int t2 = 0; t2 < TT; t2 += 2) {
        L1_STEP(t2, 0)
        L1_STEP(t2 + 1, 1)
    }
#undef L1_STEP
}

// ---------------------------------------------------------------------------
// Layer 2 forward: K=256 (x k=0..99, h k=100..249, bias k=255). 768 thr = 12
// waves, 4 tile slots/wave (tile = w + 12p, valid <= 37), jj = tile*4 + q
// (< 150). x kt0..2 MFMA'd from prefetch regs; x k=96..99 OR-merged (masked)
// into the kt3 LDS operand whose slots stay zero. h double-buffered in LDS.
__global__ __launch_bounds__(768) void l2f_scan(
    const uint4* __restrict__ frag, const u16* __restrict__ out1f,
    float* __restrict__ net)
{
    const int tid = threadIdx.x;
    const int lane = tid & 63;
    const int w = tid >> 6;
    const int q = lane >> 4;
    const int b = lane & 15;
    const int blk = blockIdx.x;
    const int b0 = blk * 16;
    const uint4* o4 = (const uint4*)out1f;

    __shared__ u16 v[2][4096];        // [buf][kt(8)*64 lanes*8 e]

    uint4 af[4][8];
    #pragma unroll
    for (int i = 0; i < 4; ++i) {
        int tile = w + 12 * i;
        if (tile <= 37)
            #pragma unroll
            for (int kt = 0; kt < 8; ++kt)
                af[i][kt] = frag[(tile * 8 + kt) * 64 + lane];
    }

    for (int idx = tid; idx < 4096; idx += 768) ((u32*)v)[idx] = 0u;

    uint4 pfA[4], pfB[4];
    #pragma unroll
    for (int ktx = 0; ktx < 4; ++ktx)
        pfA[ktx] = o4[((size_t)blk * 4 + ktx) * 64 + lane];

    __syncthreads();                  // zero-init complete before special slots
    const u16 oneh = to_h(1.0f);
    if (tid < 16) {                   // bias row k=255, both bufs
        v[0][(496 + tid) * 8 + 7] = oneh;
        v[1][(496 + tid) * 8 + 7] = oneh;
    }

    const u32 umask = (q == 0) ? 0xFFFFFFFFu : 0u;   // x k=96..99: q==0, e0..3
    int vslot[4];
    #pragma unroll
    for (int p = 0; p < 4; ++p) {
        int jj = (w + 12 * p) * 4 + q;
        int k = 100 + (jj < 150 ? jj : 0);
        vslot[p] = ((k >> 5) * 64 + ((k & 31) >> 3) * 16 + b) * 8 + (k & 7);
    }
    float c[4] = {0.f, 0.f, 0.f, 0.f};
    __syncthreads();

#define L2F_STEP(T, CUR, PFC, PFN) { \
    uint4 bfu[5]; \
    _Pragma("unroll") for (int kh = 0; kh < 5; ++kh) \
        bfu[kh] = *(const uint4*)&v[CUR][((kh + 3) * 64 + lane) * 8]; \
    const int tn = ((T) < 127) ? (T) + 1 : 127; \
    _Pragma("unroll") for (int ktx = 0; ktx < 4; ++ktx) \
        PFN[ktx] = o4[(((size_t)tn * 64 + blk) * 4 + ktx) * 64 + lane]; \
    f32x4 acc[4]; \
    _Pragma("unroll") for (int i = 0; i < 4; ++i) acc[i] = (f32x4){0.f, 0.f, 0.f, 0.f}; \
    __builtin_amdgcn_s_setprio(1); \
    _Pragma("unroll") for (int i = 0; i < 4; ++i) { \
        if (w + 12 * i <= 37) { \
            _Pragma("unroll") for (int kt = 0; kt < 3; ++kt) \
                acc[i] = mfma16(af[i][kt], PFC[kt], acc[i]); \
        } \
    } \
    bfu[0].x |= PFC[3].x & umask; \
    bfu[0].y |= PFC[3].y & umask; \
    _Pragma("unroll") for (int i = 0; i < 4; ++i) { \
        if (w + 12 * i <= 37) { \
            _Pragma("unroll") for (int kh = 0; kh < 5; ++kh) \
                acc[i] = mfma16(af[i][kh + 3], bfu[kh], acc[i]); \
        } \
    } \
    __builtin_amdgcn_s_setprio(0); \
    _Pragma("unroll") for (int p = 0; p < 4; ++p) { \
        int jj = (w + 12 * p) * 4 + q; \
        if (jj < 150) { \
            float hn = lstm_cell(acc[p][0], acc[p][1], acc[p][2], acc[p][3], c[p]); \
            v[1 - (CUR)][vslot[p]] = to_h(hn); \
            if ((T) == 127) net[(size_t)(b0 + b) * 300 + jj] = hn; \
        } \
    } \
    wg_barrier_lds(); }

    for (int t2 = 0; t2 < TT; t2 += 2) {
        L2F_STEP(t2, 0, pfA, pfB)
        L2F_STEP(t2 + 1, 1, pfB, pfA)
    }
#undef L2F_STEP
}

// ---------------------------------------------------------------------------
// Layer 2 backward = single step from zero state (Whh_b drops out).
__global__ __launch_bounds__(640, 1) void l2b_step(
    const u16* __restrict__ out1f, const float* __restrict__ WtT,
    const float* __restrict__ bias, float* __restrict__ net)   // writes [:, 150:300]
{
    const int tid = threadIdx.x;
    const int blk = blockIdx.x;
    const int b0 = blk * 16;
    __shared__ alignas(16) float x_s[100][16];
    __shared__ alignas(16) float gbuf[16][644];
    for (int idx = tid; idx < 1600; idx += 640) {
        int k2 = idx >> 4, bb = idx & 15;
        x_s[k2][bb] = from_h(out1f[((((size_t)127 * 64 + blk) * 4 + (k2 >> 5)) * 64
                                    + ((k2 & 31) >> 3) * 16 + bb) * 8 + (k2 & 7)]);
    }
    __syncthreads();
    if (tid < 600) {
        int g = tid;
        float acc[16];
        #pragma unroll
        for (int bb = 0; bb < 16; ++bb) acc[bb] = 0.f;
        for (int k = 0; k < 100; ++k) {
            float wv = WtT[k * 600 + g];
            float4 xa = *(const float4*)&x_s[k][0];
            float4 xb = *(const float4*)&x_s[k][4];
            float4 xc = *(const float4*)&x_s[k][8];
            float4 xd = *(const float4*)&x_s[k][12];
            acc[0] = fmaf(wv, xa.x, acc[0]);  acc[1] = fmaf(wv, xa.y, acc[1]);
            acc[2] = fmaf(wv, xa.z, acc[2]);  acc[3] = fmaf(wv, xa.w, acc[3]);
            acc[4] = fmaf(wv, xb.x, acc[4]);  acc[5] = fmaf(wv, xb.y, acc[5]);
            acc[6] = fmaf(wv, xb.z, acc[6]);  acc[7] = fmaf(wv, xb.w, acc[7]);
            acc[8] = fmaf(wv, xc.x, acc[8]);  acc[9] = fmaf(wv, xc.y, acc[9]);
            acc[10] = fmaf(wv, xc.z, acc[10]); acc[11] = fmaf(wv, xc.w, acc[11]);
            acc[12] = fmaf(wv, xd.x, acc[12]); acc[13] = fmaf(wv, xd.y, acc[13]);
            acc[14] = fmaf(wv, xd.z, acc[14]); acc[15] = fmaf(wv, xd.w, acc[15]);
        }
        #pragma unroll
        for (int bb = 0; bb < 16; ++bb) gbuf[bb][g] = acc[bb];
    }
    __syncthreads();
    for (int idx = tid; idx < 2400; idx += 640) {
        int j = idx >> 4, bb = idx & 15;
        float ig = gbuf[bb][j]       + bias[j];
        float gg = gbuf[bb][j + 300] + bias[j + 300];
        float og = gbuf[bb][j + 450] + bias[j + 450];
        float cn = sigm(ig) * tanh_(gg);           // c0 = 0 -> forget term vanishes
        float hn = sigm(og) * tanh_(cn);
        net[(size_t)(b0 + bb) * 300 + 150 + j] = hn;
    }
}

// waveform_feat + pef + pef_logits + feat
__global__ void head1(const float* __restrict__ net, const float* __restrict__ rrs,
                      const float* __restrict__ headW, const float* __restrict__ headb,
                      const float* __restrict__ p1W, const float* __restrict__ p1b,
                      const float* __restrict__ p2W, const float* __restrict__ p2b,
                      float* __restrict__ out)
{
    int gid = blockIdx.x * 256 + threadIdx.x;     // 4096
    int b = gid >> 2, og = gid & 3;
    float acc[5];
    #pragma unroll
    for (int o2 = 0; o2 < 5; ++o2) acc[o2] = headb[og * 5 + o2];
    const float* nb = net + (size_t)b * 300;
    for (int k = 0; k < 300; ++k) {
        float nv = nb[k];
        #pragma unroll
        for (int o2 = 0; o2 < 5; ++o2)
            acc[o2] = fmaf(headW[(og * 5 + o2) * 300 + k], nv, acc[o2]);
    }
    #pragma unroll
    for (int o2 = 0; o2 < 5; ++o2) {
        int o = og * 5 + o2;
        float vv = acc[o2] > 0.f ? acc[o2] : 0.3f * acc[o2];
        out[b * 20 + o] = vv;                  // waveform_feat
        out[22528 + b * 30 + o] = vv;          // feat[:, :20]
    }
    if (og == 0) {
        float p[10];
        #pragma unroll
        for (int r = 0; r < 10; ++r) {
            float a = p1b[r];
            #pragma unroll
            for (int qq = 0; qq < 4; ++qq) a = fmaf(p1W[r * 4 + qq], rrs[b * 4 + qq], a);
            p[r] = a > 0.f ? a : 0.3f * a;
            out[22528 + b * 30 + 20 + r] = p[r];   // feat[:, 20:30]
        }
        #pragma unroll
        for (int s = 0; s < 2; ++s) {
            float a = p2b[s];
            #pragma unroll
            for (int r = 0; r < 10; ++r) a = fmaf(p2W[s * 10 + r], p[r], a);
            out[20480 + b * 2 + s] = a;            // pef_logits
        }
    }
}

__global__ void head2(const float* __restrict__ fcW, const float* __restrict__ fcb,
                      float* __restrict__ out)
{
    int b = blockIdx.x * 256 + threadIdx.x;   // 1024
    const float* feat = out + 22528 + b * 30;
    float f[30];
    #pragma unroll
    for (int k = 0; k < 30; ++k) f[k] = feat[k];
    #pragma unroll
    for (int s = 0; s < 4; ++s) {
        float a = fcb[s];
        #pragma unroll
        for (int k = 0; k < 30; ++k) a = fmaf(fcW[s * 30 + k], f[k], a);
        out[53248 + b * 4 + s] = a;
    }
}

extern "C" void kernel_launch(void* const* d_in, const int* in_sizes, int n_in,
                              void* d_out, int out_size, void* d_ws, size_t ws_size,
                              hipStream_t stream)
{
    const float* x     = (const float*)d_in[0];
    const float* rrs   = (const float*)d_in[1];
    const float* W1ihF = (const float*)d_in[2];
    const float* W1hhF = (const float*)d_in[3];
    const float* b1F   = (const float*)d_in[4];
    const float* W1ihB = (const float*)d_in[5];
    const float* W1hhB = (const float*)d_in[6];
    const float* b1B   = (const float*)d_in[7];
    const float* W2ihF = (const float*)d_in[8];
    const float* W2hhF = (const float*)d_in[9];
    const float* b2F   = (const float*)d_in[10];
    const float* W2ihB = (const float*)d_in[11];
    // d_in[12] (l2_Whh_b) unused: backward output at t=T-1 starts from h0=0.
    const float* b2B   = (const float*)d_in[13];
    const float* headW = (const float*)d_in[14];
    const float* headb = (const float*)d_in[15];
    const float* p1W   = (const float*)d_in[16];
    const float* p1b   = (const float*)d_in[17];
    const float* p2W   = (const float*)d_in[18];
    const float* p2b   = (const float*)d_in[19];
    const float* fcW   = (const float*)d_in[20];
    const float* fcb   = (const float*)d_in[21];
    float* out = (float*)d_out;

    char* ws = (char*)d_ws;
    uint4* frag1f = (uint4*)(ws + 0);          //  32 KB (16 tiles x 2 kt)
    uint4* frag1b = (uint4*)(ws + 32768);      //  32 KB
    uint4* frag2f = (uint4*)(ws + 65536);      // 320 KB (40 tiles x 8 kt)
    float* WtT    = (float*)(ws + 393216);     // 240 KB (Wih2_b^T [100][600])
    u16*   out1f  = (u16*)(ws + 655360);       //  32 MB ([128][64][4][64][8] u16)
    float* net    = (float*)(ws + 655360 + 33554432);  // 1.2 MB ([1024][300])
    (void)ws_size; (void)in_sizes; (void)n_in; (void)out_size;

    prep_all<<<1322, 64, 0, stream>>>(W1ihF, W1hhF, b1F, W1ihB, W1hhB, b1B,
                                      W2ihF, W2hhF, b2F, W2ihB,
                                      frag1f, frag1b, frag2f, WtT);
    l1_scan<<<dim3(64, 2), 768, 0, stream>>>(x, frag1f, frag1b, out1f);
    l2f_scan<<<64, 768, 0, stream>>>(frag2f, out1f, net);
    l2b_step<<<64, 640, 0, stream>>>(out1f, WtT, b2B, net);
    head1<<<16, 256, 0, stream>>>(net, rrs, headW, headb, p1W, p1b, p2W, p2b, out);
    head2<<<4, 256, 0, stream>>>(fcW, fcb, out);
}

// Round 6
// 303.459 us; speedup vs baseline: 2.1286x; 2.1286x over previous
//
#include <hip/hip_runtime.h>

// BiLSTM on MI355X.
//  - l1_scan: 1024 thr (16 waves, 1 tile/wave, 4 waves/SIMD; tiny reg set).
//  - l2f_scan: 512 thr (8 waves, 5 tiles/wave) — weights MUST stay register-
//    resident: 2 waves/SIMD gives the 256-VGPR budget (12 waves spilled in r5).
//    Cross-step pipeline: acc_x(t+1) (x-part of gates, h-independent) computed
//    during step t's gate phase from single-buffered prefetch regs; the
//    barrier->cell critical path is only the 25 h-MFMAs.
//  - One raw barrier per step (lgkmcnt only; global ops stay in flight).
//  - l2b: backward scan's last output = single step from zero state.
//  - bias folded as an extra K-column against a constant-1.0 B row.
//  - 7-transcendental fused LSTM cell (shared-denominator form).

typedef unsigned short u16;
typedef unsigned int u32;
typedef float f32x4 __attribute__((ext_vector_type(4)));
typedef _Float16 f16x8 __attribute__((ext_vector_type(8)));
typedef short s16x8 __attribute__((ext_vector_type(8)));

#if __has_builtin(__builtin_amdgcn_mfma_f32_16x16x32_f16)
#define USE_F16 1
#else
#define USE_F16 0
#endif

#define B1 1024
#define TT 128

__device__ __forceinline__ u16 to_h(float x) {
#if USE_F16
    _Float16 h = (_Float16)x;
    return __builtin_bit_cast(u16, h);
#else
    u32 u = __builtin_bit_cast(u32, x);
    u32 r = u + 0x7FFFu + ((u >> 16) & 1u);
    return (u16)(r >> 16);
#endif
}
__device__ __forceinline__ float from_h(u16 s) {
#if USE_F16
    return (float)__builtin_bit_cast(_Float16, s);
#else
    u32 u = ((u32)s) << 16;
    return __builtin_bit_cast(float, u);
#endif
}

__device__ __forceinline__ f32x4 mfma16(uint4 a, uint4 b, f32x4 c) {
#if USE_F16
    return __builtin_amdgcn_mfma_f32_16x16x32_f16(
        __builtin_bit_cast(f16x8, a), __builtin_bit_cast(f16x8, b), c, 0, 0, 0);
#else
    return __builtin_amdgcn_mfma_f32_16x16x32_bf16(
        __builtin_bit_cast(s16x8, a), __builtin_bit_cast(s16x8, b), c, 0, 0, 0);
#endif
}

#define LOG2E 1.4426950408889634f
__device__ __forceinline__ float sigm(float x) {
    return __builtin_amdgcn_rcpf(1.f + __builtin_amdgcn_exp2f(-LOG2E * x));
}
__device__ __forceinline__ float tanh_(float x) {
    return 1.f - 2.f * __builtin_amdgcn_rcpf(1.f + __builtin_amdgcn_exp2f(2.f * LOG2E * x));
}
__device__ __forceinline__ float clampf(float x, float k) {
    return fminf(fmaxf(x, -k), k);
}

// Fused LSTM cell: c' = sigm(f)*c + sigm(i)*tanh(g); h = sigm(o)*tanh(c').
// Shared-denominator form: 5 exp2 + 2 rcp. Clamps keep products finite.
__device__ __forceinline__ float lstm_cell(float ig, float fg, float gg, float og,
                                           float& c)
{
    float ei = __builtin_amdgcn_exp2f(-LOG2E * clampf(ig, 25.f));
    float ef = __builtin_amdgcn_exp2f(-LOG2E * clampf(fg, 25.f));
    float eg = __builtin_amdgcn_exp2f(2.f * LOG2E * clampf(gg, 15.f));
    float P   = (1.f + ei) * (eg + 1.f);
    float num = fmaf(c, P, (eg - 1.f) * (1.f + ef));
    float cn  = num * __builtin_amdgcn_rcpf((1.f + ef) * P);
    c = cn;
    float eo = __builtin_amdgcn_exp2f(-LOG2E * clampf(og, 25.f));
    float ec = __builtin_amdgcn_exp2f(2.f * LOG2E * clampf(cn, 15.f));
    return (ec - 1.f) * __builtin_amdgcn_rcpf((1.f + eo) * (ec + 1.f));
}

// Raw workgroup barrier: waits only LDS ops (lgkmcnt); global loads/stores
// stay in flight across it (compiler inserts counted vmcnt at register uses).
__device__ __forceinline__ void wg_barrier_lds() {
    __builtin_amdgcn_sched_barrier(0);
    asm volatile("s_waitcnt lgkmcnt(0)" ::: "memory");
    __builtin_amdgcn_s_barrier();
    __builtin_amdgcn_sched_barrier(0);
}

// ---------------------------------------------------------------------------
// Weight packing [Wih | Whh | bias-col | 0] into MFMA A-fragments, permuted:
// tile row m = q*4 + tau maps to original weight row tau*GR + (tile*4 + q).
// Consumer thread (lane q*16+b) owning `tile` gets gates (i,f,g,o) of group
// jj = tile*4+q in acc[0..3] -> nonlinearity fully in-register.
__device__ __forceinline__ void prep_frag_body(
    const float* __restrict__ Wih, const float* __restrict__ Whh,
    const float* __restrict__ bias, uint4* __restrict__ dst,
    int GR, int KT, int x_off, int x_len, int h_off, int h_len, int bias_k,
    int bid, int l)
{
    int tile = bid / KT, kt = bid - tile * KT;
    int ml = l & 15;
    int qq = ml >> 2, tau = ml & 3;
    int jj = tile * 4 + qq;
    bool valid = jj < GR;
    int row = tau * GR + jj;
    u32 dw[4];
    #pragma unroll
    for (int d = 0; d < 4; ++d) {
        u16 hh[2];
        #pragma unroll
        for (int s = 0; s < 2; ++s) {
            int j = d * 2 + s;
            int k = kt * 32 + (l >> 4) * 8 + j;
            float val = 0.f;
            if (valid) {
                if (k >= x_off && k < x_off + x_len) val = Wih[row * x_len + (k - x_off)];
                else if (k >= h_off && k < h_off + h_len) val = Whh[row * h_len + (k - h_off)];
                else if (k == bias_k) val = bias[row];
            }
            hh[s] = to_h(val);
        }
        dw[d] = (u32)hh[0] | ((u32)hh[1] << 16);
    }
    uint4 o; o.x = dw[0]; o.y = dw[1]; o.z = dw[2]; o.w = dw[3];
    dst[bid * 64 + l] = o;
}

__global__ void prep_all(const float* __restrict__ W1ihF, const float* __restrict__ W1hhF,
                         const float* __restrict__ b1F,
                         const float* __restrict__ W1ihB, const float* __restrict__ W1hhB,
                         const float* __restrict__ b1B,
                         const float* __restrict__ W2ihF, const float* __restrict__ W2hhF,
                         const float* __restrict__ b2F, const float* __restrict__ W2ihB,
                         uint4* __restrict__ frag1f, uint4* __restrict__ frag1b,
                         uint4* __restrict__ frag2f, float* __restrict__ WtT)
{
    int bid = blockIdx.x;
    int l = threadIdx.x;
    if (bid < 32)
        prep_frag_body(W1ihF, W1hhF, b1F, frag1f, 50, 2, 0, 1, 1, 50, 63, bid, l);
    else if (bid < 64)
        prep_frag_body(W1ihB, W1hhB, b1B, frag1b, 50, 2, 0, 1, 1, 50, 63, bid - 32, l);
    else if (bid < 384)
        prep_frag_body(W2ihF, W2hhF, b2F, frag2f, 150, 8, 0, 100, 100, 150, 255, bid - 64, l);
    else {
        int idx = (bid - 384) * 64 + l;          // WtT[k][g] = W2ihB[g][k]
        if (idx < 60000) {
            int k = idx / 600, g = idx - k * 600;
            WtT[idx] = W2ihB[g * 100 + k];
        }
    }
}

// ---------------------------------------------------------------------------
// Layer 1: K=64 (x k=0, h k=1..50, bias k=63). 1024 thr = 16 waves, exactly
// one tile per wave (tiles 13..15 are zero-padded), jj = w*4 + q (< 50).
// out1f layout: u16 fragment tensor [t][blk16][ktx(4)][lane(64)][e(8)].
__global__ __launch_bounds__(1024, 4) void l1_scan(
    const float* __restrict__ x, const uint4* __restrict__ fragF,
    const uint4* __restrict__ fragB, u16* __restrict__ out1f)
{
    const int tid = threadIdx.x;
    const int lane = tid & 63;
    const int w = tid >> 6;           // 0..15 = tile
    const int q = lane >> 4;
    const int b = lane & 15;
    const int blk = blockIdx.x;
    const int dir = blockIdx.y;
    const uint4* frag = dir ? fragB : fragF;

    __shared__ u16 v[2][1024];        // [buf][kt(2)*64 lanes*8 e]
    __shared__ float x_s[128][17];    // padded: conflict-free col reads

    uint4 af0 = frag[(w * 2 + 0) * 64 + lane];
    uint4 af1 = frag[(w * 2 + 1) * 64 + lane];

    const int b0 = blk * 16;
    for (int idx = tid; idx < 1024; idx += 1024) ((u32*)v)[idx] = 0u;
    for (int idx = tid; idx < 2048; idx += 1024) {
        int bb = idx >> 7, t = idx & 127;
        x_s[t][bb] = x[(size_t)(b0 + bb) * TT + t];
    }
    __syncthreads();                  // zero-init complete before special slots
    const u16 oneh = to_h(1.0f);
    if (tid < 16) {
        v[0][(112 + tid) * 8 + 7] = oneh;             // bias row k=63, both bufs
        v[1][(112 + tid) * 8 + 7] = oneh;
        v[0][tid * 8] = to_h(x[(size_t)(b0 + tid) * TT + (dir ? TT - 1 : 0)]);
    }
    const int jj = w * 4 + q;         // valid < 50
    const int k1 = 1 + jj;
    const int vslot = ((k1 >> 5) * 64 + ((k1 & 31) >> 3) * 16 + b) * 8 + (k1 & 7);
    const int k2 = dir * 50 + (jj < 50 ? jj : 0);
    const size_t eb = (((size_t)blk * 4 + (k2 >> 5)) * 64
                       + ((k2 & 31) >> 3) * 16 + b) * 8 + (k2 & 7);
    float c = 0.f;
    __syncthreads();

#define L1_STEP(T, CUR) { \
    uint4 bf0 = *(const uint4*)&v[CUR][lane * 8]; \
    uint4 bf1 = *(const uint4*)&v[CUR][(64 + lane) * 8]; \
    f32x4 acc = (f32x4){0.f, 0.f, 0.f, 0.f}; \
    acc = mfma16(af0, bf0, acc); \
    acc = mfma16(af1, bf1, acc); \
    const int tt = dir ? 127 - (T) : (T); \
    if (jj < 50) { \
        float hn = lstm_cell(acc[0], acc[1], acc[2], acc[3], c); \
        u16 hb = to_h(hn); \
        out1f[eb + (size_t)tt * 131072] = hb; \
        v[1 - (CUR)][vslot] = hb; \
    } \
    if (tid < 16 && (T) < 127) \
        v[1 - (CUR)][tid * 8] = to_h(x_s[dir ? 126 - (T) : (T) + 1][tid]); \
    wg_barrier_lds(); }

    for (int t2 = 0; t2 < TT; t2 += 2) {
        L1_STEP(t2, 0)
        L1_STEP(t2 + 1, 1)
    }
#undef L1_STEP
}

// ---------------------------------------------------------------------------
// Layer 2 forward: K=256 (x k=0..99, h k=100..249, bias k=255). 512 thr = 8
// waves, 5 tiles/wave (tile = w + 8p), jj = tile*4 + q (< 150).
// Pipeline: acc holds acc_x(t) at step entry; h-phase adds the 25 h-MFMAs
// (kt3..7 from LDS; kt3's x-slots stay zero); cells consume acc; then acc is
// refilled with acc_x(t+1) from the single-buffered prefetch regs (loads
// issued at step start -> ~full step of latency cover). One barrier/step.
__global__ __launch_bounds__(512, 2) void l2f_scan(
    const uint4* __restrict__ frag, const u16* __restrict__ out1f,
    float* __restrict__ net)
{
    const int tid = threadIdx.x;
    const int lane = tid & 63;
    const int w = tid >> 6;           // 0..7
    const int q = lane >> 4;
    const int b = lane & 15;
    const int blk = blockIdx.x;
    const int b0 = blk * 16;
    const uint4* o4 = (const uint4*)out1f;

    __shared__ u16 v[2][4096];        // [buf][kt(8)*64 lanes*8 e]

    uint4 af[5][8];
    #pragma unroll
    for (int i = 0; i < 5; ++i)
        #pragma unroll
        for (int kt = 0; kt < 8; ++kt)
            af[i][kt] = frag[((w + 8 * i) * 8 + kt) * 64 + lane];

    for (int idx = tid; idx < 4096; idx += 512) ((u32*)v)[idx] = 0u;

    uint4 pf[4];
    #pragma unroll
    for (int ktx = 0; ktx < 4; ++ktx)
        pf[ktx] = o4[((size_t)blk * 4 + ktx) * 64 + lane];   // x(0)

    __syncthreads();                  // zero-init complete before special slots
    const u16 oneh = to_h(1.0f);
    if (tid < 16) {                   // bias row k=255, both bufs
        v[0][(496 + tid) * 8 + 7] = oneh;
        v[1][(496 + tid) * 8 + 7] = oneh;
    }

    const u32 umask = (q == 0) ? 0xFFFFFFFFu : 0u;   // x k=96..99: q==0, e0..3
    int vslot[5];
    #pragma unroll
    for (int p = 0; p < 5; ++p) {
        int jj = (w + 8 * p) * 4 + q;
        int k = 100 + (jj < 150 ? jj : 0);
        vslot[p] = ((k >> 5) * 64 + ((k & 31) >> 3) * 16 + b) * 8 + (k & 7);
    }
    float c[5] = {0.f, 0.f, 0.f, 0.f, 0.f};

    // Prologue: acc = acc_x(0)
    f32x4 acc[5];
    {
        uint4 xm; xm.x = pf[3].x & umask; xm.y = pf[3].y & umask; xm.z = 0u; xm.w = 0u;
        #pragma unroll
        for (int p = 0; p < 5; ++p) {
            acc[p] = mfma16(af[p][0], pf[0], (f32x4){0.f, 0.f, 0.f, 0.f});
            acc[p] = mfma16(af[p][1], pf[1], acc[p]);
            acc[p] = mfma16(af[p][2], pf[2], acc[p]);
            acc[p] = mfma16(af[p][3], xm, acc[p]);
        }
    }
    __syncthreads();

#define L2F_STEP(T, CUR) { \
    const int tn = ((T) < 127) ? (T) + 1 : 127; \
    _Pragma("unroll") for (int ktx = 0; ktx < 4; ++ktx) \
        pf[ktx] = o4[(((size_t)tn * 64 + blk) * 4 + ktx) * 64 + lane]; \
    uint4 bfu[5]; \
    _Pragma("unroll") for (int kh = 0; kh < 5; ++kh) \
        bfu[kh] = *(const uint4*)&v[CUR][((kh + 3) * 64 + lane) * 8]; \
    __builtin_amdgcn_s_setprio(1); \
    _Pragma("unroll") for (int kh = 0; kh < 5; ++kh) { \
        _Pragma("unroll") for (int i = 0; i < 5; ++i) \
            acc[i] = mfma16(af[i][kh + 3], bfu[kh], acc[i]); \
    } \
    __builtin_amdgcn_s_setprio(0); \
    uint4 xm; xm.x = pf[3].x & umask; xm.y = pf[3].y & umask; xm.z = 0u; xm.w = 0u; \
    _Pragma("unroll") for (int p = 0; p < 5; ++p) { \
        int jj = (w + 8 * p) * 4 + q; \
        if (jj < 150) { \
            float hn = lstm_cell(acc[p][0], acc[p][1], acc[p][2], acc[p][3], c[p]); \
            v[1 - (CUR)][vslot[p]] = to_h(hn); \
            if ((T) == 127) net[(size_t)(b0 + b) * 300 + jj] = hn; \
        } \
        acc[p] = mfma16(af[p][0], pf[0], (f32x4){0.f, 0.f, 0.f, 0.f}); \
        acc[p] = mfma16(af[p][1], pf[1], acc[p]); \
        acc[p] = mfma16(af[p][2], pf[2], acc[p]); \
        acc[p] = mfma16(af[p][3], xm, acc[p]); \
    } \
    wg_barrier_lds(); }

    for (int t2 = 0; t2 < TT; t2 += 2) {
        L2F_STEP(t2, 0)
        L2F_STEP(t2 + 1, 1)
    }
#undef L2F_STEP
}

// ---------------------------------------------------------------------------
// Layer 2 backward = single step from zero state (Whh_b drops out).
__global__ __launch_bounds__(640, 1) void l2b_step(
    const u16* __restrict__ out1f, const float* __restrict__ WtT,
    const float* __restrict__ bias, float* __restrict__ net)   // writes [:, 150:300]
{
    const int tid = threadIdx.x;
    const int blk = blockIdx.x;
    const int b0 = blk * 16;
    __shared__ alignas(16) float x_s[100][16];
    __shared__ alignas(16) float gbuf[16][644];
    for (int idx = tid; idx < 1600; idx += 640) {
        int k2 = idx >> 4, bb = idx & 15;
        x_s[k2][bb] = from_h(out1f[((((size_t)127 * 64 + blk) * 4 + (k2 >> 5)) * 64
                                    + ((k2 & 31) >> 3) * 16 + bb) * 8 + (k2 & 7)]);
    }
    __syncthreads();
    if (tid < 600) {
        int g = tid;
        float acc[16];
        #pragma unroll
        for (int bb = 0; bb < 16; ++bb) acc[bb] = 0.f;
        for (int k = 0; k < 100; ++k) {
            float wv = WtT[k * 600 + g];
            float4 xa = *(const float4*)&x_s[k][0];
            float4 xb = *(const float4*)&x_s[k][4];
            float4 xc = *(const float4*)&x_s[k][8];
            float4 xd = *(const float4*)&x_s[k][12];
            acc[0] = fmaf(wv, xa.x, acc[0]);  acc[1] = fmaf(wv, xa.y, acc[1]);
            acc[2] = fmaf(wv, xa.z, acc[2]);  acc[3] = fmaf(wv, xa.w, acc[3]);
            acc[4] = fmaf(wv, xb.x, acc[4]);  acc[5] = fmaf(wv, xb.y, acc[5]);
            acc[6] = fmaf(wv, xb.z, acc[6]);  acc[7] = fmaf(wv, xb.w, acc[7]);
            acc[8] = fmaf(wv, xc.x, acc[8]);  acc[9] = fmaf(wv, xc.y, acc[9]);
            acc[10] = fmaf(wv, xc.z, acc[10]); acc[11] = fmaf(wv, xc.w, acc[11]);
            acc[12] = fmaf(wv, xd.x, acc[12]); acc[13] = fmaf(wv, xd.y, acc[13]);
            acc[14] = fmaf(wv, xd.z, acc[14]); acc[15] = fmaf(wv, xd.w, acc[15]);
        }
        #pragma unroll
        for (int bb = 0; bb < 16; ++bb) gbuf[bb][g] = acc[bb];
    }
    __syncthreads();
    for (int idx = tid; idx < 2400; idx += 640) {
        int j = idx >> 4, bb = idx & 15;
        float ig = gbuf[bb][j]       + bias[j];
        float gg = gbuf[bb][j + 300] + bias[j + 300];
        float og = gbuf[bb][j + 450] + bias[j + 450];
        float cn = sigm(ig) * tanh_(gg);           // c0 = 0 -> forget term vanishes
        float hn = sigm(og) * tanh_(cn);
        net[(size_t)(b0 + bb) * 300 + 150 + j] = hn;
    }
}

// waveform_feat + pef + pef_logits + feat
__global__ void head1(const float* __restrict__ net, const float* __restrict__ rrs,
                      const float* __restrict__ headW, const float* __restrict__ headb,
                      const float* __restrict__ p1W, const float* __restrict__ p1b,
                      const float* __restrict__ p2W, const float* __restrict__ p2b,
                      float* __restrict__ out)
{
    int gid = blockIdx.x * 256 + threadIdx.x;     // 4096
    int b = gid >> 2, og = gid & 3;
    float acc[5];
    #pragma unroll
    for (int o2 = 0; o2 < 5; ++o2) acc[o2] = headb[og * 5 + o2];
    const float* nb = net + (size_t)b * 300;
    for (int k = 0; k < 300; ++k) {
        float nv = nb[k];
        #pragma unroll
        for (int o2 = 0; o2 < 5; ++o2)
            acc[o2] = fmaf(headW[(og * 5 + o2) * 300 + k], nv, acc[o2]);
    }
    #pragma unroll
    for (int o2 = 0; o2 < 5; ++o2) {
        int o = og * 5 + o2;
        float vv = acc[o2] > 0.f ? acc[o2] : 0.3f * acc[o2];
        out[b * 20 + o] = vv;                  // waveform_feat
        out[22528 + b * 30 + o] = vv;          // feat[:, :20]
    }
    if (og == 0) {
        float p[10];
        #pragma unroll
        for (int r = 0; r < 10; ++r) {
            float a = p1b[r];
            #pragma unroll
            for (int qq = 0; qq < 4; ++qq) a = fmaf(p1W[r * 4 + qq], rrs[b * 4 + qq], a);
            p[r] = a > 0.f ? a : 0.3f * a;
            out[22528 + b * 30 + 20 + r] = p[r];   // feat[:, 20:30]
        }
        #pragma unroll
        for (int s = 0; s < 2; ++s) {
            float a = p2b[s];
            #pragma unroll
            for (int r = 0; r < 10; ++r) a = fmaf(p2W[s * 10 + r], p[r], a);
            out[20480 + b * 2 + s] = a;            // pef_logits
        }
    }
}

__global__ void head2(const float* __restrict__ fcW, const float* __restrict__ fcb,
                      float* __restrict__ out)
{
    int b = blockIdx.x * 256 + threadIdx.x;   // 1024
    const float* feat = out + 22528 + b * 30;
    float f[30];
    #pragma unroll
    for (int k = 0; k < 30; ++k) f[k] = feat[k];
    #pragma unroll
    for (int s = 0; s < 4; ++s) {
        float a = fcb[s];
        #pragma unroll
        for (int k = 0; k < 30; ++k) a = fmaf(fcW[s * 30 + k], f[k], a);
        out[53248 + b * 4 + s] = a;
    }
}

extern "C" void kernel_launch(void* const* d_in, const int* in_sizes, int n_in,
                              void* d_out, int out_size, void* d_ws, size_t ws_size,
                              hipStream_t stream)
{
    const float* x     = (const float*)d_in[0];
    const float* rrs   = (const float*)d_in[1];
    const float* W1ihF = (const float*)d_in[2];
    const float* W1hhF = (const float*)d_in[3];
    const float* b1F   = (const float*)d_in[4];
    const float* W1ihB = (const float*)d_in[5];
    const float* W1hhB = (const float*)d_in[6];
    const float* b1B   = (const float*)d_in[7];
    const float* W2ihF = (const float*)d_in[8];
    const float* W2hhF = (const float*)d_in[9];
    const float* b2F   = (const float*)d_in[10];
    const float* W2ihB = (const float*)d_in[11];
    // d_in[12] (l2_Whh_b) unused: backward output at t=T-1 starts from h0=0.
    const float* b2B   = (const float*)d_in[13];
    const float* headW = (const float*)d_in[14];
    const float* headb = (const float*)d_in[15];
    const float* p1W   = (const float*)d_in[16];
    const float* p1b   = (const float*)d_in[17];
    const float* p2W   = (const float*)d_in[18];
    const float* p2b   = (const float*)d_in[19];
    const float* fcW   = (const float*)d_in[20];
    const float* fcb   = (const float*)d_in[21];
    float* out = (float*)d_out;

    char* ws = (char*)d_ws;
    uint4* frag1f = (uint4*)(ws + 0);          //  32 KB (16 tiles x 2 kt)
    uint4* frag1b = (uint4*)(ws + 32768);      //  32 KB
    uint4* frag2f = (uint4*)(ws + 65536);      // 320 KB (40 tiles x 8 kt)
    float* WtT    = (float*)(ws + 393216);     // 240 KB (Wih2_b^T [100][600])
    u16*   out1f  = (u16*)(ws + 655360);       //  32 MB ([128][64][4][64][8] u16)
    float* net    = (float*)(ws + 655360 + 33554432);  // 1.2 MB ([1024][300])
    (void)ws_size; (void)in_sizes; (void)n_in; (void)out_size;

    prep_all<<<1322, 64, 0, stream>>>(W1ihF, W1hhF, b1F, W1ihB, W1hhB, b1B,
                                      W2ihF, W2hhF, b2F, W2ihB,
                                      frag1f, frag1b, frag2f, WtT);
    l1_scan<<<dim3(64, 2), 1024, 0, stream>>>(x, frag1f, frag1b, out1f);
    l2f_scan<<<64, 512, 0, stream>>>(frag2f, out1f, net);
    l2b_step<<<64, 640, 0, stream>>>(out1f, WtT, b2B, net);
    head1<<<16, 256, 0, stream>>>(net, rrs, headW, headb, p1W, p1b, p2W, p2b, out);
    head2<<<4, 256, 0, stream>>>(fcW, fcb, out);
}

// Round 7
// 301.516 us; speedup vs baseline: 2.1423x; 1.0064x over previous
//
#include <hip/hip_runtime.h>

// BiLSTM on MI355X.
//  - KEY FIX (r7): pin weight MFMA fragments in VGPRs via empty asm "+v" ties.
//    r4-r6 showed VGPR_Count=120 with af[5][8]=160 regs needed and no scratch
//    traffic -> compiler was REMATERIALIZING the weight loads inside the step
//    loop (320KB/block/step from L2). Pinning forces true residency.
//  - l1_scan: 1024 thr (16 waves, 1 tile/wave); l2f_scan: 512 thr (8 waves,
//    5 tiles/wave, 2 waves/SIMD -> 256-VGPR budget).
//  - Cross-step pipeline in l2f: acc_x(t+1) computed during step t's tail.
//  - One raw barrier per step (lgkmcnt only; global ops stay in flight).
//  - l2b: backward scan's last output = single step from zero state.
//  - bias folded as an extra K-column against a constant-1.0 B row.
//  - Fused LSTM cell: 5 exp2 + 2 rcp, clamps only on tanh args (g, c).

typedef unsigned short u16;
typedef unsigned int u32;
typedef float f32x4 __attribute__((ext_vector_type(4)));
typedef _Float16 f16x8 __attribute__((ext_vector_type(8)));
typedef short s16x8 __attribute__((ext_vector_type(8)));

#if __has_builtin(__builtin_amdgcn_mfma_f32_16x16x32_f16)
#define USE_F16 1
#else
#define USE_F16 0
#endif

#define B1 1024
#define TT 128

// Pin a uint4's components as asm-defined values: the register allocator can
// no longer rematerialize the originating load inside the loop.
#define PIN4(V) asm volatile("" : "+v"((V).x), "+v"((V).y), "+v"((V).z), "+v"((V).w))

__device__ __forceinline__ u16 to_h(float x) {
#if USE_F16
    _Float16 h = (_Float16)x;
    return __builtin_bit_cast(u16, h);
#else
    u32 u = __builtin_bit_cast(u32, x);
    u32 r = u + 0x7FFFu + ((u >> 16) & 1u);
    return (u16)(r >> 16);
#endif
}
__device__ __forceinline__ float from_h(u16 s) {
#if USE_F16
    return (float)__builtin_bit_cast(_Float16, s);
#else
    u32 u = ((u32)s) << 16;
    return __builtin_bit_cast(float, u);
#endif
}

__device__ __forceinline__ f32x4 mfma16(uint4 a, uint4 b, f32x4 c) {
#if USE_F16
    return __builtin_amdgcn_mfma_f32_16x16x32_f16(
        __builtin_bit_cast(f16x8, a), __builtin_bit_cast(f16x8, b), c, 0, 0, 0);
#else
    return __builtin_amdgcn_mfma_f32_16x16x32_bf16(
        __builtin_bit_cast(s16x8, a), __builtin_bit_cast(s16x8, b), c, 0, 0, 0);
#endif
}

#define LOG2E 1.4426950408889634f
__device__ __forceinline__ float sigm(float x) {
    return __builtin_amdgcn_rcpf(1.f + __builtin_amdgcn_exp2f(-LOG2E * x));
}
__device__ __forceinline__ float tanh_(float x) {
    return 1.f - 2.f * __builtin_amdgcn_rcpf(1.f + __builtin_amdgcn_exp2f(2.f * LOG2E * x));
}
__device__ __forceinline__ float clampf(float x, float k) {
    return fminf(fmaxf(x, -k), k);    // -> v_med3_f32
}

// Fused LSTM cell: c' = sigm(f)*c + sigm(i)*tanh(g); h = sigm(o)*tanh(c').
// Shared-denominator form: 5 exp2 + 2 rcp. Clamps only where the doubled
// exponent can overflow f32 (g, c'); sigmoid-path exp2 is finite for |x|<80.
__device__ __forceinline__ float lstm_cell(float ig, float fg, float gg, float og,
                                           float& c)
{
    float ei = __builtin_amdgcn_exp2f(-LOG2E * ig);
    float ef = __builtin_amdgcn_exp2f(-LOG2E * fg);
    float eg = __builtin_amdgcn_exp2f(2.f * LOG2E * clampf(gg, 15.f));
    float P   = (1.f + ei) * (eg + 1.f);
    float num = fmaf(c, P, (eg - 1.f) * (1.f + ef));
    float cn  = num * __builtin_amdgcn_rcpf((1.f + ef) * P);
    c = cn;
    float eo = __builtin_amdgcn_exp2f(-LOG2E * og);
    float ec = __builtin_amdgcn_exp2f(2.f * LOG2E * clampf(cn, 15.f));
    return (ec - 1.f) * __builtin_amdgcn_rcpf((1.f + eo) * (ec + 1.f));
}

// Raw workgroup barrier: waits only LDS ops (lgkmcnt); global loads/stores
// stay in flight across it (compiler inserts counted vmcnt at register uses).
__device__ __forceinline__ void wg_barrier_lds() {
    __builtin_amdgcn_sched_barrier(0);
    asm volatile("s_waitcnt lgkmcnt(0)" ::: "memory");
    __builtin_amdgcn_s_barrier();
    __builtin_amdgcn_sched_barrier(0);
}

// ---------------------------------------------------------------------------
// Weight packing [Wih | Whh | bias-col | 0] into MFMA A-fragments, permuted:
// tile row m = q*4 + tau maps to original weight row tau*GR + (tile*4 + q).
// Consumer thread (lane q*16+b) owning `tile` gets gates (i,f,g,o) of group
// jj = tile*4+q in acc[0..3] -> nonlinearity fully in-register.
__device__ __forceinline__ void prep_frag_body(
    const float* __restrict__ Wih, const float* __restrict__ Whh,
    const float* __restrict__ bias, uint4* __restrict__ dst,
    int GR, int KT, int x_off, int x_len, int h_off, int h_len, int bias_k,
    int bid, int l)
{
    int tile = bid / KT, kt = bid - tile * KT;
    int ml = l & 15;
    int qq = ml >> 2, tau = ml & 3;
    int jj = tile * 4 + qq;
    bool valid = jj < GR;
    int row = tau * GR + jj;
    u32 dw[4];
    #pragma unroll
    for (int d = 0; d < 4; ++d) {
        u16 hh[2];
        #pragma unroll
        for (int s = 0; s < 2; ++s) {
            int j = d * 2 + s;
            int k = kt * 32 + (l >> 4) * 8 + j;
            float val = 0.f;
            if (valid) {
                if (k >= x_off && k < x_off + x_len) val = Wih[row * x_len + (k - x_off)];
                else if (k >= h_off && k < h_off + h_len) val = Whh[row * h_len + (k - h_off)];
                else if (k == bias_k) val = bias[row];
            }
            hh[s] = to_h(val);
        }
        dw[d] = (u32)hh[0] | ((u32)hh[1] << 16);
    }
    uint4 o; o.x = dw[0]; o.y = dw[1]; o.z = dw[2]; o.w = dw[3];
    dst[bid * 64 + l] = o;
}

__global__ void prep_all(const float* __restrict__ W1ihF, const float* __restrict__ W1hhF,
                         const float* __restrict__ b1F,
                         const float* __restrict__ W1ihB, const float* __restrict__ W1hhB,
                         const float* __restrict__ b1B,
                         const float* __restrict__ W2ihF, const float* __restrict__ W2hhF,
                         const float* __restrict__ b2F, const float* __restrict__ W2ihB,
                         uint4* __restrict__ frag1f, uint4* __restrict__ frag1b,
                         uint4* __restrict__ frag2f, float* __restrict__ WtT)
{
    int bid = blockIdx.x;
    int l = threadIdx.x;
    if (bid < 32)
        prep_frag_body(W1ihF, W1hhF, b1F, frag1f, 50, 2, 0, 1, 1, 50, 63, bid, l);
    else if (bid < 64)
        prep_frag_body(W1ihB, W1hhB, b1B, frag1b, 50, 2, 0, 1, 1, 50, 63, bid - 32, l);
    else if (bid < 384)
        prep_frag_body(W2ihF, W2hhF, b2F, frag2f, 150, 8, 0, 100, 100, 150, 255, bid - 64, l);
    else {
        int idx = (bid - 384) * 64 + l;          // WtT[k][g] = W2ihB[g][k]
        if (idx < 60000) {
            int k = idx / 600, g = idx - k * 600;
            WtT[idx] = W2ihB[g * 100 + k];
        }
    }
}

// ---------------------------------------------------------------------------
// Layer 1: K=64 (x k=0, h k=1..50, bias k=63). 1024 thr = 16 waves, exactly
// one tile per wave (tiles 13..15 zero-padded), jj = w*4 + q (< 50).
// out1f layout: u16 fragment tensor [t][blk16][ktx(4)][lane(64)][e(8)].
__global__ __launch_bounds__(1024, 4) void l1_scan(
    const float* __restrict__ x, const uint4* __restrict__ fragF,
    const uint4* __restrict__ fragB, u16* __restrict__ out1f)
{
    const int tid = threadIdx.x;
    const int lane = tid & 63;
    const int w = tid >> 6;           // 0..15 = tile
    const int q = lane >> 4;
    const int b = lane & 15;
    const int blk = blockIdx.x;
    const int dir = blockIdx.y;
    const uint4* frag = dir ? fragB : fragF;

    __shared__ u16 v[2][1024];        // [buf][kt(2)*64 lanes*8 e]
    __shared__ float x_s[128][17];    // padded: conflict-free col reads

    uint4 af0 = frag[(w * 2 + 0) * 64 + lane];
    uint4 af1 = frag[(w * 2 + 1) * 64 + lane];
    PIN4(af0); PIN4(af1);             // forbid in-loop reload

    const int b0 = blk * 16;
    for (int idx = tid; idx < 1024; idx += 1024) ((u32*)v)[idx] = 0u;
    for (int idx = tid; idx < 2048; idx += 1024) {
        int bb = idx >> 7, t = idx & 127;
        x_s[t][bb] = x[(size_t)(b0 + bb) * TT + t];
    }
    __syncthreads();                  // zero-init complete before special slots
    const u16 oneh = to_h(1.0f);
    if (tid < 16) {
        v[0][(112 + tid) * 8 + 7] = oneh;             // bias row k=63, both bufs
        v[1][(112 + tid) * 8 + 7] = oneh;
        v[0][tid * 8] = to_h(x[(size_t)(b0 + tid) * TT + (dir ? TT - 1 : 0)]);
    }
    const int jj = w * 4 + q;         // valid < 50
    const int k1 = 1 + jj;
    const int vslot = ((k1 >> 5) * 64 + ((k1 & 31) >> 3) * 16 + b) * 8 + (k1 & 7);
    const int k2 = dir * 50 + (jj < 50 ? jj : 0);
    const size_t eb = (((size_t)blk * 4 + (k2 >> 5)) * 64
                       + ((k2 & 31) >> 3) * 16 + b) * 8 + (k2 & 7);
    float c = 0.f;
    __syncthreads();

#define L1_STEP(T, CUR) { \
    uint4 bf0 = *(const uint4*)&v[CUR][lane * 8]; \
    uint4 bf1 = *(const uint4*)&v[CUR][(64 + lane) * 8]; \
    f32x4 acc = (f32x4){0.f, 0.f, 0.f, 0.f}; \
    acc = mfma16(af0, bf0, acc); \
    acc = mfma16(af1, bf1, acc); \
    const int tt = dir ? 127 - (T) : (T); \
    if (jj < 50) { \
        float hn = lstm_cell(acc[0], acc[1], acc[2], acc[3], c); \
        u16 hb = to_h(hn); \
        out1f[eb + (size_t)tt * 131072] = hb; \
        v[1 - (CUR)][vslot] = hb; \
    } \
    if (tid < 16 && (T) < 127) \
        v[1 - (CUR)][tid * 8] = to_h(x_s[dir ? 126 - (T) : (T) + 1][tid]); \
    wg_barrier_lds(); }

    for (int t2 = 0; t2 < TT; t2 += 2) {
        L1_STEP(t2, 0)
        L1_STEP(t2 + 1, 1)
    }
#undef L1_STEP
}

// ---------------------------------------------------------------------------
// Layer 2 forward: K=256 (x k=0..99, h k=100..249, bias k=255). 512 thr = 8
// waves, 5 tiles/wave (tile = w + 8p), jj = tile*4 + q (< 150).
// Pipeline: acc holds acc_x(t) at step entry; h-phase adds the 25 h-MFMAs;
// cells consume acc; acc refilled with acc_x(t+1) from prefetch regs during
// the barrier tail. One barrier/step. Weights pinned in VGPRs (160 regs).
__global__ __launch_bounds__(512, 2) void l2f_scan(
    const uint4* __restrict__ frag, const u16* __restrict__ out1f,
    float* __restrict__ net)
{
    const int tid = threadIdx.x;
    const int lane = tid & 63;
    const int w = tid >> 6;           // 0..7
    const int q = lane >> 4;
    const int b = lane & 15;
    const int blk = blockIdx.x;
    const int b0 = blk * 16;
    const uint4* o4 = (const uint4*)out1f;

    __shared__ u16 v[2][4096];        // [buf][kt(8)*64 lanes*8 e]

    uint4 af[5][8];
    #pragma unroll
    for (int i = 0; i < 5; ++i)
        #pragma unroll
        for (int kt = 0; kt < 8; ++kt) {
            af[i][kt] = frag[((w + 8 * i) * 8 + kt) * 64 + lane];
            PIN4(af[i][kt]);          // forbid in-loop reload (the r4-r6 stall)
        }

    for (int idx = tid; idx < 4096; idx += 512) ((u32*)v)[idx] = 0u;

    uint4 pf[4];
    #pragma unroll
    for (int ktx = 0; ktx < 4; ++ktx)
        pf[ktx] = o4[((size_t)blk * 4 + ktx) * 64 + lane];   // x(0)

    __syncthreads();                  // zero-init complete before special slots
    const u16 oneh = to_h(1.0f);
    if (tid < 16) {                   // bias row k=255, both bufs
        v[0][(496 + tid) * 8 + 7] = oneh;
        v[1][(496 + tid) * 8 + 7] = oneh;
    }

    const u32 umask = (q == 0) ? 0xFFFFFFFFu : 0u;   // x k=96..99: q==0, e0..3
    int vslot[5];
    #pragma unroll
    for (int p = 0; p < 5; ++p) {
        int jj = (w + 8 * p) * 4 + q;
        int k = 100 + (jj < 150 ? jj : 0);
        vslot[p] = ((k >> 5) * 64 + ((k & 31) >> 3) * 16 + b) * 8 + (k & 7);
    }
    float c[5] = {0.f, 0.f, 0.f, 0.f, 0.f};

    // Prologue: acc = acc_x(0)
    f32x4 acc[5];
    {
        uint4 xm; xm.x = pf[3].x & umask; xm.y = pf[3].y & umask; xm.z = 0u; xm.w = 0u;
        #pragma unroll
        for (int p = 0; p < 5; ++p) {
            acc[p] = mfma16(af[p][0], pf[0], (f32x4){0.f, 0.f, 0.f, 0.f});
            acc[p] = mfma16(af[p][1], pf[1], acc[p]);
            acc[p] = mfma16(af[p][2], pf[2], acc[p]);
            acc[p] = mfma16(af[p][3], xm, acc[p]);
        }
    }
    __syncthreads();

#define L2F_STEP(T, CUR) { \
    const int tn = ((T) < 127) ? (T) + 1 : 127; \
    _Pragma("unroll") for (int ktx = 0; ktx < 4; ++ktx) \
        pf[ktx] = o4[(((size_t)tn * 64 + blk) * 4 + ktx) * 64 + lane]; \
    uint4 bfu[5]; \
    _Pragma("unroll") for (int kh = 0; kh < 5; ++kh) \
        bfu[kh] = *(const uint4*)&v[CUR][((kh + 3) * 64 + lane) * 8]; \
    __builtin_amdgcn_s_setprio(1); \
    _Pragma("unroll") for (int kh = 0; kh < 5; ++kh) { \
        _Pragma("unroll") for (int i = 0; i < 5; ++i) \
            acc[i] = mfma16(af[i][kh + 3], bfu[kh], acc[i]); \
    } \
    __builtin_amdgcn_s_setprio(0); \
    uint4 xm; xm.x = pf[3].x & umask; xm.y = pf[3].y & umask; xm.z = 0u; xm.w = 0u; \
    _Pragma("unroll") for (int p = 0; p < 5; ++p) { \
        int jj = (w + 8 * p) * 4 + q; \
        if (jj < 150) { \
            float hn = lstm_cell(acc[p][0], acc[p][1], acc[p][2], acc[p][3], c[p]); \
            v[1 - (CUR)][vslot[p]] = to_h(hn); \
            if ((T) == 127) net[(size_t)(b0 + b) * 300 + jj] = hn; \
        } \
        acc[p] = mfma16(af[p][0], pf[0], (f32x4){0.f, 0.f, 0.f, 0.f}); \
        acc[p] = mfma16(af[p][1], pf[1], acc[p]); \
        acc[p] = mfma16(af[p][2], pf[2], acc[p]); \
        acc[p] = mfma16(af[p][3], xm, acc[p]); \
    } \
    wg_barrier_lds(); }

    for (int t2 = 0; t2 < TT; t2 += 2) {
        L2F_STEP(t2, 0)
        L2F_STEP(t2 + 1, 1)
    }
#undef L2F_STEP
}

// ---------------------------------------------------------------------------
// Layer 2 backward = single step from zero state (Whh_b drops out).
__global__ __launch_bounds__(640, 1) void l2b_step(
    const u16* __restrict__ out1f, const float* __restrict__ WtT,
    const float* __restrict__ bias, float* __restrict__ net)   // writes [:, 150:300]
{
    const int tid = threadIdx.x;
    const int blk = blockIdx.x;
    const int b0 = blk * 16;
    __shared__ alignas(16) float x_s[100][16];
    __shared__ alignas(16) float gbuf[16][644];
    for (int idx = tid; idx < 1600; idx += 640) {
        int k2 = idx >> 4, bb = idx & 15;
        x_s[k2][bb] = from_h(out1f[((((size_t)127 * 64 + blk) * 4 + (k2 >> 5)) * 64
                                    + ((k2 & 31) >> 3) * 16 + bb) * 8 + (k2 & 7)]);
    }
    __syncthreads();
    if (tid < 600) {
        int g = tid;
        float acc[16];
        #pragma unroll
        for (int bb = 0; bb < 16; ++bb) acc[bb] = 0.f;
        for (int k = 0; k < 100; ++k) {
            float wv = WtT[k * 600 + g];
            float4 xa = *(const float4*)&x_s[k][0];
            float4 xb = *(const float4*)&x_s[k][4];
            float4 xc = *(const float4*)&x_s[k][8];
            float4 xd = *(const float4*)&x_s[k][12];
            acc[0] = fmaf(wv, xa.x, acc[0]);  acc[1] = fmaf(wv, xa.y, acc[1]);
            acc[2] = fmaf(wv, xa.z, acc[2]);  acc[3] = fmaf(wv, xa.w, acc[3]);
            acc[4] = fmaf(wv, xb.x, acc[4]);  acc[5] = fmaf(wv, xb.y, acc[5]);
            acc[6] = fmaf(wv, xb.z, acc[6]);  acc[7] = fmaf(wv, xb.w, acc[7]);
            acc[8] = fmaf(wv, xc.x, acc[8]);  acc[9] = fmaf(wv, xc.y, acc[9]);
            acc[10] = fmaf(wv, xc.z, acc[10]); acc[11] = fmaf(wv, xc.w, acc[11]);
            acc[12] = fmaf(wv, xd.x, acc[12]); acc[13] = fmaf(wv, xd.y, acc[13]);
            acc[14] = fmaf(wv, xd.z, acc[14]); acc[15] = fmaf(wv, xd.w, acc[15]);
        }
        #pragma unroll
        for (int bb = 0; bb < 16; ++bb) gbuf[bb][g] = acc[bb];
    }
    __syncthreads();
    for (int idx = tid; idx < 2400; idx += 640) {
        int j = idx >> 4, bb = idx & 15;
        float ig = gbuf[bb][j]       + bias[j];
        float gg = gbuf[bb][j + 300] + bias[j + 300];
        float og = gbuf[bb][j + 450] + bias[j + 450];
        float cn = sigm(ig) * tanh_(gg);           // c0 = 0 -> forget term vanishes
        float hn = sigm(og) * tanh_(cn);
        net[(size_t)(b0 + bb) * 300 + 150 + j] = hn;
    }
}

// waveform_feat + pef + pef_logits + feat
__global__ void head1(const float* __restrict__ net, const float* __restrict__ rrs,
                      const float* __restrict__ headW, const float* __restrict__ headb,
                      const float* __restrict__ p1W, const float* __restrict__ p1b,
                      const float* __restrict__ p2W, const float* __restrict__ p2b,
                      float* __restrict__ out)
{
    int gid = blockIdx.x * 256 + threadIdx.x;     // 4096
    int b = gid >> 2, og = gid & 3;
    float acc[5];
    #pragma unroll
    for (int o2 = 0; o2 < 5; ++o2) acc[o2] = headb[og * 5 + o2];
    const float* nb = net + (size_t)b * 300;
    for (int k = 0; k < 300; ++k) {
        float nv = nb[k];
        #pragma unroll
        for (int o2 = 0; o2 < 5; ++o2)
            acc[o2] = fmaf(headW[(og * 5 + o2) * 300 + k], nv, acc[o2]);
    }
    #pragma unroll
    for (int o2 = 0; o2 < 5; ++o2) {
        int o = og * 5 + o2;
        float vv = acc[o2] > 0.f ? acc[o2] : 0.3f * acc[o2];
        out[b * 20 + o] = vv;                  // waveform_feat
        out[22528 + b * 30 + o] = vv;          // feat[:, :20]
    }
    if (og == 0) {
        float p[10];
        #pragma unroll
        for (int r = 0; r < 10; ++r) {
            float a = p1b[r];
            #pragma unroll
            for (int qq = 0; qq < 4; ++qq) a = fmaf(p1W[r * 4 + qq], rrs[b * 4 + qq], a);
            p[r] = a > 0.f ? a : 0.3f * a;
            out[22528 + b * 30 + 20 + r] = p[r];   // feat[:, 20:30]
        }
        #pragma unroll
        for (int s = 0; s < 2; ++s) {
            float a = p2b[s];
            #pragma unroll
            for (int r = 0; r < 10; ++r) a = fmaf(p2W[s * 10 + r], p[r], a);
            out[20480 + b * 2 + s] = a;            // pef_logits
        }
    }
}

__global__ void head2(const float* __restrict__ fcW, const float* __restrict__ fcb,
                      float* __restrict__ out)
{
    int b = blockIdx.x * 256 + threadIdx.x;   // 1024
    const float* feat = out + 22528 + b * 30;
    float f[30];
    #pragma unroll
    for (int k = 0; k < 30; ++k) f[k] = feat[k];
    #pragma unroll
    for (int s = 0; s < 4; ++s) {
        float a = fcb[s];
        #pragma unroll
        for (int k = 0; k < 30; ++k) a = fmaf(fcW[s * 30 + k], f[k], a);
        out[53248 + b * 4 + s] = a;
    }
}

extern "C" void kernel_launch(void* const* d_in, const int* in_sizes, int n_in,
                              void* d_out, int out_size, void* d_ws, size_t ws_size,
                              hipStream_t stream)
{
    const float* x     = (const float*)d_in[0];
    const float* rrs   = (const float*)d_in[1];
    const float* W1ihF = (const float*)d_in[2];
    const float* W1hhF = (const float*)d_in[3];
    const float* b1F   = (const float*)d_in[4];
    const float* W1ihB = (const float*)d_in[5];
    const float* W1hhB = (const float*)d_in[6];
    const float* b1B   = (const float*)d_in[7];
    const float* W2ihF = (const float*)d_in[8];
    const float* W2hhF = (const float*)d_in[9];
    const float* b2F   = (const float*)d_in[10];
    const float* W2ihB = (const float*)d_in[11];
    // d_in[12] (l2_Whh_b) unused: backward output at t=T-1 starts from h0=0.
    const float* b2B   = (const float*)d_in[13];
    const float* headW = (const float*)d_in[14];
    const float* headb = (const float*)d_in[15];
    const float* p1W   = (const float*)d_in[16];
    const float* p1b   = (const float*)d_in[17];
    const float* p2W   = (const float*)d_in[18];
    const float* p2b   = (const float*)d_in[19];
    const float* fcW   = (const float*)d_in[20];
    const float* fcb   = (const float*)d_in[21];
    float* out = (float*)d_out;

    char* ws = (char*)d_ws;
    uint4* frag1f = (uint4*)(ws + 0);          //  32 KB (16 tiles x 2 kt)
    uint4* frag1b = (uint4*)(ws + 32768);      //  32 KB
    uint4* frag2f = (uint4*)(ws + 65536);      // 320 KB (40 tiles x 8 kt)
    float* WtT    = (float*)(ws + 393216);     // 240 KB (Wih2_b^T [100][600])
    u16*   out1f  = (u16*)(ws + 655360);       //  32 MB ([128][64][4][64][8] u16)
    float* net    = (float*)(ws + 655360 + 33554432);  // 1.2 MB ([1024][300])
    (void)ws_size; (void)in_sizes; (void)n_in; (void)out_size;

    prep_all<<<1322, 64, 0, stream>>>(W1ihF, W1hhF, b1F, W1ihB, W1hhB, b1B,
                                      W2ihF, W2hhF, b2F, W2ihB,
                                      frag1f, frag1b, frag2f, WtT);
    l1_scan<<<dim3(64, 2), 1024, 0, stream>>>(x, frag1f, frag1b, out1f);
    l2f_scan<<<64, 512, 0, stream>>>(frag2f, out1f, net);
    l2b_step<<<64, 640, 0, stream>>>(out1f, WtT, b2B, net);
    head1<<<16, 256, 0, stream>>>(net, rrs, headW, headb, p1W, p1b, p2W, p2b, out);
    head2<<<4, 256, 0, stream>>>(fcW, fcb, out);
}

// Round 8
// 301.391 us; speedup vs baseline: 2.1432x; 1.0004x over previous
//
#include <hip/hip_runtime.h>

// BiLSTM on MI355X.
//  - KEY FIX (r7): pin weight MFMA fragments in VGPRs via empty asm "+v" ties.
//    r4-r6 showed VGPR_Count=120 with af[5][8]=160 regs needed and no scratch
//    traffic -> compiler was REMATERIALIZING the weight loads inside the step
//    loop (320KB/block/step from L2). Pinning forces true residency.
//  - l1_scan: 1024 thr (16 waves, 1 tile/wave); l2f_scan: 512 thr (8 waves,
//    5 tiles/wave, 2 waves/SIMD -> 256-VGPR budget).
//  - Cross-step pipeline in l2f: acc_x(t+1) computed during step t's tail.
//  - One raw barrier per step (lgkmcnt only; global ops stay in flight).
//  - l2b: backward scan's last output = single step from zero state.
//  - bias folded as an extra K-column against a constant-1.0 B row.
//  - Fused LSTM cell: 5 exp2 + 2 rcp, clamps only on tanh args (g, c).

typedef unsigned short u16;
typedef unsigned int u32;
typedef float f32x4 __attribute__((ext_vector_type(4)));
typedef _Float16 f16x8 __attribute__((ext_vector_type(8)));
typedef short s16x8 __attribute__((ext_vector_type(8)));

#if __has_builtin(__builtin_amdgcn_mfma_f32_16x16x32_f16)
#define USE_F16 1
#else
#define USE_F16 0
#endif

#define B1 1024
#define TT 128

// Pin a uint4's components as asm-defined values: the register allocator can
// no longer rematerialize the originating load inside the loop.
#define PIN4(V) asm volatile("" : "+v"((V).x), "+v"((V).y), "+v"((V).z), "+v"((V).w))

__device__ __forceinline__ u16 to_h(float x) {
#if USE_F16
    _Float16 h = (_Float16)x;
    return __builtin_bit_cast(u16, h);
#else
    u32 u = __builtin_bit_cast(u32, x);
    u32 r = u + 0x7FFFu + ((u >> 16) & 1u);
    return (u16)(r >> 16);
#endif
}
__device__ __forceinline__ float from_h(u16 s) {
#if USE_F16
    return (float)__builtin_bit_cast(_Float16, s);
#else
    u32 u = ((u32)s) << 16;
    return __builtin_bit_cast(float, u);
#endif
}

__device__ __forceinline__ f32x4 mfma16(uint4 a, uint4 b, f32x4 c) {
#if USE_F16
    return __builtin_amdgcn_mfma_f32_16x16x32_f16(
        __builtin_bit_cast(f16x8, a), __builtin_bit_cast(f16x8, b), c, 0, 0, 0);
#else
    return __builtin_amdgcn_mfma_f32_16x16x32_bf16(
        __builtin_bit_cast(s16x8, a), __builtin_bit_cast(s16x8, b), c, 0, 0, 0);
#endif
}

#define LOG2E 1.4426950408889634f
__device__ __forceinline__ float sigm(float x) {
    return __builtin_amdgcn_rcpf(1.f + __builtin_amdgcn_exp2f(-LOG2E * x));
}
__device__ __forceinline__ float tanh_(float x) {
    return 1.f - 2.f * __builtin_amdgcn_rcpf(1.f + __builtin_amdgcn_exp2f(2.f * LOG2E * x));
}
__device__ __forceinline__ float clampf(float x, float k) {
    return fminf(fmaxf(x, -k), k);    // -> v_med3_f32
}

// Fused LSTM cell: c' = sigm(f)*c + sigm(i)*tanh(g); h = sigm(o)*tanh(c').
// Shared-denominator form: 5 exp2 + 2 rcp. Clamps only where the doubled
// exponent can overflow f32 (g, c'); sigmoid-path exp2 is finite for |x|<80.
__device__ __forceinline__ float lstm_cell(float ig, float fg, float gg, float og,
                                           float& c)
{
    float ei = __builtin_amdgcn_exp2f(-LOG2E * ig);
    float ef = __builtin_amdgcn_exp2f(-LOG2E * fg);
    float eg = __builtin_amdgcn_exp2f(2.f * LOG2E * clampf(gg, 15.f));
    float P   = (1.f + ei) * (eg + 1.f);
    float num = fmaf(c, P, (eg - 1.f) * (1.f + ef));
    float cn  = num * __builtin_amdgcn_rcpf((1.f + ef) * P);
    c = cn;
    float eo = __builtin_amdgcn_exp2f(-LOG2E * og);
    float ec = __builtin_amdgcn_exp2f(2.f * LOG2E * clampf(cn, 15.f));
    return (ec - 1.f) * __builtin_amdgcn_rcpf((1.f + eo) * (ec + 1.f));
}

// Raw workgroup barrier: waits only LDS ops (lgkmcnt); global loads/stores
// stay in flight across it (compiler inserts counted vmcnt at register uses).
__device__ __forceinline__ void wg_barrier_lds() {
    __builtin_amdgcn_sched_barrier(0);
    asm volatile("s_waitcnt lgkmcnt(0)" ::: "memory");
    __builtin_amdgcn_s_barrier();
    __builtin_amdgcn_sched_barrier(0);
}

// ---------------------------------------------------------------------------
// Weight packing [Wih | Whh | bias-col | 0] into MFMA A-fragments, permuted:
// tile row m = q*4 + tau maps to original weight row tau*GR + (tile*4 + q).
// Consumer thread (lane q*16+b) owning `tile` gets gates (i,f,g,o) of group
// jj = tile*4+q in acc[0..3] -> nonlinearity fully in-register.
__device__ __forceinline__ void prep_frag_body(
    const float* __restrict__ Wih, const float* __restrict__ Whh,
    const float* __restrict__ bias, uint4* __restrict__ dst,
    int GR, int KT, int x_off, int x_len, int h_off, int h_len, int bias_k,
    int bid, int l)
{
    int tile = bid / KT, kt = bid - tile * KT;
    int ml = l & 15;
    int qq = ml >> 2, tau = ml & 3;
    int jj = tile * 4 + qq;
    bool valid = jj < GR;
    int row = tau * GR + jj;
    u32 dw[4];
    #pragma unroll
    for (int d = 0; d < 4; ++d) {
        u16 hh[2];
        #pragma unroll
        for (int s = 0; s < 2; ++s) {
            int j = d * 2 + s;
            int k = kt * 32 + (l >> 4) * 8 + j;
            float val = 0.f;
            if (valid) {
                if (k >= x_off && k < x_off + x_len) val = Wih[row * x_len + (k - x_off)];
                else if (k >= h_off && k < h_off + h_len) val = Whh[row * h_len + (k - h_off)];
                else if (k == bias_k) val = bias[row];
            }
            hh[s] = to_h(val);
        }
        dw[d] = (u32)hh[0] | ((u32)hh[1] << 16);
    }
    uint4 o; o.x = dw[0]; o.y = dw[1]; o.z = dw[2]; o.w = dw[3];
    dst[bid * 64 + l] = o;
}

__global__ void prep_all(const float* __restrict__ W1ihF, const float* __restrict__ W1hhF,
                         const float* __restrict__ b1F,
                         const float* __restrict__ W1ihB, const float* __restrict__ W1hhB,
                         const float* __restrict__ b1B,
                         const float* __restrict__ W2ihF, const float* __restrict__ W2hhF,
                         const float* __restrict__ b2F, const float* __restrict__ W2ihB,
                         uint4* __restrict__ frag1f, uint4* __restrict__ frag1b,
                         uint4* __restrict__ frag2f, float* __restrict__ WtT)
{
    int bid = blockIdx.x;
    int l = threadIdx.x;
    if (bid < 32)
        prep_frag_body(W1ihF, W1hhF, b1F, frag1f, 50, 2, 0, 1, 1, 50, 63, bid, l);
    else if (bid < 64)
        prep_frag_body(W1ihB, W1hhB, b1B, frag1b, 50, 2, 0, 1, 1, 50, 63, bid - 32, l);
    else if (bid < 384)
        prep_frag_body(W2ihF, W2hhF, b2F, frag2f, 150, 8, 0, 100, 100, 150, 255, bid - 64, l);
    else {
        int idx = (bid - 384) * 64 + l;          // WtT[k][g] = W2ihB[g][k]
        if (idx < 60000) {
            int k = idx / 600, g = idx - k * 600;
            WtT[idx] = W2ihB[g * 100 + k];
        }
    }
}

// ---------------------------------------------------------------------------
// Layer 1: K=64 (x k=0, h k=1..50, bias k=63). 1024 thr = 16 waves, exactly
// one tile per wave (tiles 13..15 zero-padded), jj = w*4 + q (< 50).
// out1f layout: u16 fragment tensor [t][blk16][ktx(4)][lane(64)][e(8)].
__global__ __launch_bounds__(1024, 4) void l1_scan(
    const float* __restrict__ x, const uint4* __restrict__ fragF,
    const uint4* __restrict__ fragB, u16* __restrict__ out1f)
{
    const int tid = threadIdx.x;
    const int lane = tid & 63;
    const int w = tid >> 6;           // 0..15 = tile
    const int q = lane >> 4;
    const int b = lane & 15;
    const int blk = blockIdx.x;
    const int dir = blockIdx.y;
    const uint4* frag = dir ? fragB : fragF;

    __shared__ u16 v[2][1024];        // [buf][kt(2)*64 lanes*8 e]
    __shared__ float x_s[128][17];    // padded: conflict-free col reads

    uint4 af0 = frag[(w * 2 + 0) * 64 + lane];
    uint4 af1 = frag[(w * 2 + 1) * 64 + lane];
    PIN4(af0); PIN4(af1);             // forbid in-loop reload

    const int b0 = blk * 16;
    for (int idx = tid; idx < 1024; idx += 1024) ((u32*)v)[idx] = 0u;
    for (int idx = tid; idx < 2048; idx += 1024) {
        int bb = idx >> 7, t = idx & 127;
        x_s[t][bb] = x[(size_t)(b0 + bb) * TT + t];
    }
    __syncthreads();                  // zero-init complete before special slots
    const u16 oneh = to_h(1.0f);
    if (tid < 16) {
        v[0][(112 + tid) * 8 + 7] = oneh;             // bias row k=63, both bufs
        v[1][(112 + tid) * 8 + 7] = oneh;
        v[0][tid * 8] = to_h(x[(size_t)(b0 + tid) * TT + (dir ? TT - 1 : 0)]);
    }
    const int jj = w * 4 + q;         // valid < 50
    const int k1 = 1 + jj;
    const int vslot = ((k1 >> 5) * 64 + ((k1 & 31) >> 3) * 16 + b) * 8 + (k1 & 7);
    const int k2 = dir * 50 + (jj < 50 ? jj : 0);
    const size_t eb = (((size_t)blk * 4 + (k2 >> 5)) * 64
                       + ((k2 & 31) >> 3) * 16 + b) * 8 + (k2 & 7);
    float c = 0.f;
    __syncthreads();

#define L1_STEP(T, CUR) { \
    uint4 bf0 = *(const uint4*)&v[CUR][lane * 8]; \
    uint4 bf1 = *(const uint4*)&v[CUR][(64 + lane) * 8]; \
    f32x4 acc = (f32x4){0.f, 0.f, 0.f, 0.f}; \
    acc = mfma16(af0, bf0, acc); \
    acc = mfma16(af1, bf1, acc); \
    const int tt = dir ? 127 - (T) : (T); \
    if (jj < 50) { \
        float hn = lstm_cell(acc[0], acc[1], acc[2], acc[3], c); \
        u16 hb = to_h(hn); \
        out1f[eb + (size_t)tt * 131072] = hb; \
        v[1 - (CUR)][vslot] = hb; \
    } \
    if (tid < 16 && (T) < 127) \
        v[1 - (CUR)][tid * 8] = to_h(x_s[dir ? 126 - (T) : (T) + 1][tid]); \
    wg_barrier_lds(); }

    for (int t2 = 0; t2 < TT; t2 += 2) {
        L1_STEP(t2, 0)
        L1_STEP(t2 + 1, 1)
    }
#undef L1_STEP
}

// ---------------------------------------------------------------------------
// Layer 2 forward: K=256 (x k=0..99, h k=100..249, bias k=255). 512 thr = 8
// waves, 5 tiles/wave (tile = w + 8p), jj = tile*4 + q (< 150).
// Pipeline: acc holds acc_x(t) at step entry; h-phase adds the 25 h-MFMAs;
// cells consume acc; acc refilled with acc_x(t+1) from prefetch regs during
// the barrier tail. One barrier/step. Weights pinned in VGPRs (160 regs).
__global__ __launch_bounds__(512, 2) void l2f_scan(
    const uint4* __restrict__ frag, const u16* __restrict__ out1f,
    float* __restrict__ net)
{
    const int tid = threadIdx.x;
    const int lane = tid & 63;
    const int w = tid >> 6;           // 0..7
    const int q = lane >> 4;
    const int b = lane & 15;
    const int blk = blockIdx.x;
    const int b0 = blk * 16;
    const uint4* o4 = (const uint4*)out1f;

    __shared__ u16 v[2][4096];        // [buf][kt(8)*64 lanes*8 e]

    uint4 af[5][8];
    #pragma unroll
    for (int i = 0; i < 5; ++i)
        #pragma unroll
        for (int kt = 0; kt < 8; ++kt) {
            af[i][kt] = frag[((w + 8 * i) * 8 + kt) * 64 + lane];
            PIN4(af[i][kt]);          // forbid in-loop reload (the r4-r6 stall)
        }

    for (int idx = tid; idx < 4096; idx += 512) ((u32*)v)[idx] = 0u;

    uint4 pf[4];
    #pragma unroll
    for (int ktx = 0; ktx < 4; ++ktx)
        pf[ktx] = o4[((size_t)blk * 4 + ktx) * 64 + lane];   // x(0)

    __syncthreads();                  // zero-init complete before special slots
    const u16 oneh = to_h(1.0f);
    if (tid < 16) {                   // bias row k=255, both bufs
        v[0][(496 + tid) * 8 + 7] = oneh;
        v[1][(496 + tid) * 8 + 7] = oneh;
    }

    const u32 umask = (q == 0) ? 0xFFFFFFFFu : 0u;   // x k=96..99: q==0, e0..3
    int vslot[5];
    #pragma unroll
    for (int p = 0; p < 5; ++p) {
        int jj = (w + 8 * p) * 4 + q;
        int k = 100 + (jj < 150 ? jj : 0);
        vslot[p] = ((k >> 5) * 64 + ((k & 31) >> 3) * 16 + b) * 8 + (k & 7);
    }
    float c[5] = {0.f, 0.f, 0.f, 0.f, 0.f};

    // Prologue: acc = acc_x(0)
    f32x4 acc[5];
    {
        uint4 xm; xm.x = pf[3].x & umask; xm.y = pf[3].y & umask; xm.z = 0u; xm.w = 0u;
        #pragma unroll
        for (int p = 0; p < 5; ++p) {
            acc[p] = mfma16(af[p][0], pf[0], (f32x4){0.f, 0.f, 0.f, 0.f});
            acc[p] = mfma16(af[p][1], pf[1], acc[p]);
            acc[p] = mfma16(af[p][2], pf[2], acc[p]);
            acc[p] = mfma16(af[p][3], xm, acc[p]);
        }
    }
    __syncthreads();

#define L2F_STEP(T, CUR) { \
    const int tn = ((T) < 127) ? (T) + 1 : 127; \
    _Pragma("unroll") for (int ktx = 0; ktx < 4; ++ktx) \
        pf[ktx] = o4[(((size_t)tn * 64 + blk) * 4 + ktx) * 64 + lane]; \
    uint4 bfu[5]; \
    _Pragma("unroll") for (int kh = 0; kh < 5; ++kh) \
        bfu[kh] = *(const uint4*)&v[CUR][((kh + 3) * 64 + lane) * 8]; \
    __builtin_amdgcn_s_setprio(1); \
    _Pragma("unroll") for (int kh = 0; kh < 5; ++kh) { \
        _Pragma("unroll") for (int i = 0; i < 5; ++i) \
            acc[i] = mfma16(af[i][kh + 3], bfu[kh], acc[i]); \
    } \
    __builtin_amdgcn_s_setprio(0); \
    uint4 xm; xm.x = pf[3].x & umask; xm.y = pf[3].y & umask; xm.z = 0u; xm.w = 0u; \
    _Pragma("unroll") for (int p = 0; p < 5; ++p) { \
        int jj = (w + 8 * p) * 4 + q; \
        if (jj < 150) { \
            float hn = lstm_cell(acc[p][0], acc[p][1], acc[p][2], acc[p][3], c[p]); \
            v[1 - (CUR)][vslot[p]] = to_h(hn); \
            if ((T) == 127) net[(size_t)(b0 + b) * 300 + jj] = hn; \
        } \
        acc[p] = mfma16(af[p][0], pf[0], (f32x4){0.f, 0.f, 0.f, 0.f}); \
        acc[p] = mfma16(af[p][1], pf[1], acc[p]); \
        acc[p] = mfma16(af[p][2], pf[2], acc[p]); \
        acc[p] = mfma16(af[p][3], xm, acc[p]); \
    } \
    wg_barrier_lds(); }

    for (int t2 = 0; t2 < TT; t2 += 2) {
        L2F_STEP(t2, 0)
        L2F_STEP(t2 + 1, 1)
    }
#undef L2F_STEP
}

// ---------------------------------------------------------------------------
// Layer 2 backward = single step from zero state (Whh_b drops out).
__global__ __launch_bounds__(640, 1) void l2b_step(
    const u16* __restrict__ out1f, const float* __restrict__ WtT,
    const float* __restrict__ bias, float* __restrict__ net)   // writes [:, 150:300]
{
    const int tid = threadIdx.x;
    const int blk = blockIdx.x;
    const int b0 = blk * 16;
    __shared__ alignas(16) float x_s[100][16];
    __shared__ alignas(16) float gbuf[16][644];
    for (int idx = tid; idx < 1600; idx += 640) {
        int k2 = idx >> 4, bb = idx & 15;
        x_s[k2][bb] = from_h(out1f[((((size_t)127 * 64 + blk) * 4 + (k2 >> 5)) * 64
                                    + ((k2 & 31) >> 3) * 16 + bb) * 8 + (k2 & 7)]);
    }
    __syncthreads();
    if (tid < 600) {
        int g = tid;
        float acc[16];
        #pragma unroll
        for (int bb = 0; bb < 16; ++bb) acc[bb] = 0.f;
        for (int k = 0; k < 100; ++k) {
            float wv = WtT[k * 600 + g];
            float4 xa = *(const float4*)&x_s[k][0];
            float4 xb = *(const float4*)&x_s[k][4];
            float4 xc = *(const float4*)&x_s[k][8];
            float4 xd = *(const float4*)&x_s[k][12];
            acc[0] = fmaf(wv, xa.x, acc[0]);  acc[1] = fmaf(wv, xa.y, acc[1]);
            acc[2] = fmaf(wv, xa.z, acc[2]);  acc[3] = fmaf(wv, xa.w, acc[3]);
            acc[4] = fmaf(wv, xb.x, acc[4]);  acc[5] = fmaf(wv, xb.y, acc[5]);
            acc[6] = fmaf(wv, xb.z, acc[6]);  acc[7] = fmaf(wv, xb.w, acc[7]);
            acc[8] = fmaf(wv, xc.x, acc[8]);  acc[9] = fmaf(wv, xc.y, acc[9]);
            acc[10] = fmaf(wv, xc.z, acc[10]); acc[11] = fmaf(wv, xc.w, acc[11]);
            acc[12] = fmaf(wv, xd.x, acc[12]); acc[13] = fmaf(wv, xd.y, acc[13]);
            acc[14] = fmaf(wv, xd.z, acc[14]); acc[15] = fmaf(wv, xd.w, acc[15]);
        }
        #pragma unroll
        for (int bb = 0; bb < 16; ++bb) gbuf[bb][g] = acc[bb];
    }
    __syncthreads();
    for (int idx = tid; idx < 2400; idx += 640) {
        int j = idx >> 4, bb = idx & 15;
        float ig = gbuf[bb][j]       + bias[j];
        float gg = gbuf[bb][j + 300] + bias[j + 300];
        float og = gbuf[bb][j + 450] + bias[j + 450];
        float cn = sigm(ig) * tanh_(gg);           // c0 = 0 -> forget term vanishes
        float hn = sigm(og) * tanh_(cn);
        net[(size_t)(b0 + bb) * 300 + 150 + j] = hn;
    }
}

// waveform_feat + pef + pef_logits + feat
__global__ void head1(const float* __restrict__ net, const float* __restrict__ rrs,
                      const float* __restrict__ headW, const float* __restrict__ headb,
                      const float* __restrict__ p1W, const float* __restrict__ p1b,
                      const float* __restrict__ p2W, const float* __restrict__ p2b,
                      float* __restrict__ out)
{
    int gid = blockIdx.x * 256 + threadIdx.x;     // 4096
    int b = gid >> 2, og = gid & 3;
    float acc[5];
    #pragma unroll
    for (int o2 = 0; o2 < 5; ++o2) acc[o2] = headb[og * 5 + o2];
    const float* nb = net + (size_t)b * 300;
    for (int k = 0; k < 300; ++k) {
        float nv = nb[k];
        #pragma unroll
        for (int o2 = 0; o2 < 5; ++o2)
            acc[o2] = fmaf(headW[(og * 5 + o2) * 300 + k], nv, acc[o2]);
    }
    #pragma unroll
    for (int o2 = 0; o2 < 5; ++o2) {
        int o = og * 5 + o2;
        float vv = acc[o2] > 0.f ? acc[o2] : 0.3f * acc[o2];
        out[b * 20 + o] = vv;                  // waveform_feat
        out[22528 + b * 30 + o] = vv;          // feat[:, :20]
    }
    if (og == 0) {
        float p[10];
        #pragma unroll
        for (int r = 0; r < 10; ++r) {
            float a = p1b[r];
            #pragma unroll
            for (int qq = 0; qq < 4; ++qq) a = fmaf(p1W[r * 4 + qq], rrs[b * 4 + qq], a);
            p[r] = a > 0.f ? a : 0.3f * a;
            out[22528 + b * 30 + 20 + r] = p[r];   // feat[:, 20:30]
        }
        #pragma unroll
        for (int s = 0; s < 2; ++s) {
            float a = p2b[s];
            #pragma unroll
            for (int r = 0; r < 10; ++r) a = fmaf(p2W[s * 10 + r], p[r], a);
            out[20480 + b * 2 + s] = a;            // pef_logits
        }
    }
}

__global__ void head2(const float* __restrict__ fcW, const float* __restrict__ fcb,
                      float* __restrict__ out)
{
    int b = blockIdx.x * 256 + threadIdx.x;   // 1024
    const float* feat = out + 22528 + b * 30;
    float f[30];
    #pragma unroll
    for (int k = 0; k < 30; ++k) f[k] = feat[k];
    #pragma unroll
    for (int s = 0; s < 4; ++s) {
        float a = fcb[s];
        #pragma unroll
        for (int k = 0; k < 30; ++k) a = fmaf(fcW[s * 30 + k], f[k], a);
        out[53248 + b * 4 + s] = a;
    }
}

extern "C" void kernel_launch(void* const* d_in, const int* in_sizes, int n_in,
                              void* d_out, int out_size, void* d_ws, size_t ws_size,
                              hipStream_t stream)
{
    const float* x     = (const float*)d_in[0];
    const float* rrs   = (const float*)d_in[1];
    const float* W1ihF = (const float*)d_in[2];
    const float* W1hhF = (const float*)d_in[3];
    const float* b1F   = (const float*)d_in[4];
    const float* W1ihB = (const float*)d_in[5];
    const float* W1hhB = (const float*)d_in[6];
    const float* b1B   = (const float*)d_in[7];
    const float* W2ihF = (const float*)d_in[8];
    const float* W2hhF = (const float*)d_in[9];
    const float* b2F   = (const float*)d_in[10];
    const float* W2ihB = (const float*)d_in[11];
    // d_in[12] (l2_Whh_b) unused: backward output at t=T-1 starts from h0=0.
    const float* b2B   = (const float*)d_in[13];
    const float* headW = (const float*)d_in[14];
    const float* headb = (const float*)d_in[15];
    const float* p1W   = (const float*)d_in[16];
    const float* p1b   = (const float*)d_in[17];
    const float* p2W   = (const float*)d_in[18];
    const float* p2b   = (const float*)d_in[19];
    const float* fcW   = (const float*)d_in[20];
    const float* fcb   = (const float*)d_in[21];
    float* out = (float*)d_out;

    char* ws = (char*)d_ws;
    uint4* frag1f = (uint4*)(ws + 0);          //  32 KB (16 tiles x 2 kt)
    uint4* frag1b = (uint4*)(ws + 32768);      //  32 KB
    uint4* frag2f = (uint4*)(ws + 65536);      // 320 KB (40 tiles x 8 kt)
    float* WtT    = (float*)(ws + 393216);     // 240 KB (Wih2_b^T [100][600])
    u16*   out1f  = (u16*)(ws + 655360);       //  32 MB ([128][64][4][64][8] u16)
    float* net    = (float*)(ws + 655360 + 33554432);  // 1.2 MB ([1024][300])
    (void)ws_size; (void)in_sizes; (void)n_in; (void)out_size;

    prep_all<<<1322, 64, 0, stream>>>(W1ihF, W1hhF, b1F, W1ihB, W1hhB, b1B,
                                      W2ihF, W2hhF, b2F, W2ihB,
                                      frag1f, frag1b, frag2f, WtT);
    l1_scan<<<dim3(64, 2), 1024, 0, stream>>>(x, frag1f, frag1b, out1f);
    l2f_scan<<<64, 512, 0, stream>>>(frag2f, out1f, net);
    l2b_step<<<64, 640, 0, stream>>>(out1f, WtT, b2B, net);
    head1<<<16, 256, 0, stream>>>(net, rrs, headW, headb, p1W, p1b, p2W, p2b, out);
    head2<<<4, 256, 0, stream>>>(fcW, fcb, out);
}

// Round 9
// 290.538 us; speedup vs baseline: 2.2232x; 1.0374x over previous
//
#include <hip/hip_runtime.h>

// BiLSTM on MI355X.
//  - l1_scan: 1024 thr (16 waves, 1 tile/wave), barrier-locked double-buffer.
//  - l2f_scan: 512 thr (8 waves, 5 tiles/wave, 2 waves/SIMD). r9: removed
//    setprio/PIN4 fences; per-p interleave {h-MFMAs, cell, ds_write} so cell
//    VALU/trans overlaps the next p's MFMAs; x k=96..99 fed via LDS write
//    (saves the masked xm MFMA, 45->40 MFMAs/wave); x-refill MFMAs late for
//    prefetch cover. One raw lgkmcnt-only barrier per step.
//  - l2b: backward scan's last output = single step from zero state.
//  - bias folded as an extra K-column against a constant-1.0 B row.
//  - Fused LSTM cell: 5 exp2 + 2 rcp, clamps only on tanh args.

typedef unsigned short u16;
typedef unsigned int u32;
typedef float f32x4 __attribute__((ext_vector_type(4)));
typedef _Float16 f16x8 __attribute__((ext_vector_type(8)));
typedef short s16x8 __attribute__((ext_vector_type(8)));

#if __has_builtin(__builtin_amdgcn_mfma_f32_16x16x32_f16)
#define USE_F16 1
#else
#define USE_F16 0
#endif

#define B1 1024
#define TT 128

__device__ __forceinline__ u16 to_h(float x) {
#if USE_F16
    _Float16 h = (_Float16)x;
    return __builtin_bit_cast(u16, h);
#else
    u32 u = __builtin_bit_cast(u32, x);
    u32 r = u + 0x7FFFu + ((u >> 16) & 1u);
    return (u16)(r >> 16);
#endif
}
__device__ __forceinline__ float from_h(u16 s) {
#if USE_F16
    return (float)__builtin_bit_cast(_Float16, s);
#else
    u32 u = ((u32)s) << 16;
    return __builtin_bit_cast(float, u);
#endif
}

__device__ __forceinline__ f32x4 mfma16(uint4 a, uint4 b, f32x4 c) {
#if USE_F16
    return __builtin_amdgcn_mfma_f32_16x16x32_f16(
        __builtin_bit_cast(f16x8, a), __builtin_bit_cast(f16x8, b), c, 0, 0, 0);
#else
    return __builtin_amdgcn_mfma_f32_16x16x32_bf16(
        __builtin_bit_cast(s16x8, a), __builtin_bit_cast(s16x8, b), c, 0, 0, 0);
#endif
}

#define LOG2E 1.4426950408889634f
__device__ __forceinline__ float sigm(float x) {
    return __builtin_amdgcn_rcpf(1.f + __builtin_amdgcn_exp2f(-LOG2E * x));
}
__device__ __forceinline__ float tanh_(float x) {
    return 1.f - 2.f * __builtin_amdgcn_rcpf(1.f + __builtin_amdgcn_exp2f(2.f * LOG2E * x));
}
__device__ __forceinline__ float clampf(float x, float k) {
    return fminf(fmaxf(x, -k), k);    // -> v_med3_f32
}

// Fused LSTM cell: c' = sigm(f)*c + sigm(i)*tanh(g); h = sigm(o)*tanh(c').
// Shared-denominator form: 5 exp2 + 2 rcp. Clamps only where the doubled
// exponent can overflow f32 (g, c'); sigmoid-path exp2 is finite for |x|<80.
__device__ __forceinline__ float lstm_cell(float ig, float fg, float gg, float og,
                                           float& c)
{
    float ei = __builtin_amdgcn_exp2f(-LOG2E * ig);
    float ef = __builtin_amdgcn_exp2f(-LOG2E * fg);
    float eg = __builtin_amdgcn_exp2f(2.f * LOG2E * clampf(gg, 15.f));
    float P   = (1.f + ei) * (eg + 1.f);
    float num = fmaf(c, P, (eg - 1.f) * (1.f + ef));
    float cn  = num * __builtin_amdgcn_rcpf((1.f + ef) * P);
    c = cn;
    float eo = __builtin_amdgcn_exp2f(-LOG2E * og);
    float ec = __builtin_amdgcn_exp2f(2.f * LOG2E * clampf(cn, 15.f));
    return (ec - 1.f) * __builtin_amdgcn_rcpf((1.f + eo) * (ec + 1.f));
}

// Raw workgroup barrier: waits only LDS ops (lgkmcnt); global loads/stores
// stay in flight across it (compiler inserts counted vmcnt at register uses).
__device__ __forceinline__ void wg_barrier_lds() {
    __builtin_amdgcn_sched_barrier(0);
    asm volatile("s_waitcnt lgkmcnt(0)" ::: "memory");
    __builtin_amdgcn_s_barrier();
    __builtin_amdgcn_sched_barrier(0);
}

// ---------------------------------------------------------------------------
// Weight packing [Wih | Whh | bias-col | 0] into MFMA A-fragments, permuted:
// tile row m = q*4 + tau maps to original weight row tau*GR + (tile*4 + q).
__device__ __forceinline__ void prep_frag_body(
    const float* __restrict__ Wih, const float* __restrict__ Whh,
    const float* __restrict__ bias, uint4* __restrict__ dst,
    int GR, int KT, int x_off, int x_len, int h_off, int h_len, int bias_k,
    int bid, int l)
{
    int tile = bid / KT, kt = bid - tile * KT;
    int ml = l & 15;
    int qq = ml >> 2, tau = ml & 3;
    int jj = tile * 4 + qq;
    bool valid = jj < GR;
    int row = tau * GR + jj;
    u32 dw[4];
    #pragma unroll
    for (int d = 0; d < 4; ++d) {
        u16 hh[2];
        #pragma unroll
        for (int s = 0; s < 2; ++s) {
            int j = d * 2 + s;
            int k = kt * 32 + (l >> 4) * 8 + j;
            float val = 0.f;
            if (valid) {
                if (k >= x_off && k < x_off + x_len) val = Wih[row * x_len + (k - x_off)];
                else if (k >= h_off && k < h_off + h_len) val = Whh[row * h_len + (k - h_off)];
                else if (k == bias_k) val = bias[row];
            }
            hh[s] = to_h(val);
        }
        dw[d] = (u32)hh[0] | ((u32)hh[1] << 16);
    }
    uint4 o; o.x = dw[0]; o.y = dw[1]; o.z = dw[2]; o.w = dw[3];
    dst[bid * 64 + l] = o;
}

__global__ void prep_all(const float* __restrict__ W1ihF, const float* __restrict__ W1hhF,
                         const float* __restrict__ b1F,
                         const float* __restrict__ W1ihB, const float* __restrict__ W1hhB,
                         const float* __restrict__ b1B,
                         const float* __restrict__ W2ihF, const float* __restrict__ W2hhF,
                         const float* __restrict__ b2F, const float* __restrict__ W2ihB,
                         uint4* __restrict__ frag1f, uint4* __restrict__ frag1b,
                         uint4* __restrict__ frag2f, float* __restrict__ WtT)
{
    int bid = blockIdx.x;
    int l = threadIdx.x;
    if (bid < 32)
        prep_frag_body(W1ihF, W1hhF, b1F, frag1f, 50, 2, 0, 1, 1, 50, 63, bid, l);
    else if (bid < 64)
        prep_frag_body(W1ihB, W1hhB, b1B, frag1b, 50, 2, 0, 1, 1, 50, 63, bid - 32, l);
    else if (bid < 384)
        prep_frag_body(W2ihF, W2hhF, b2F, frag2f, 150, 8, 0, 100, 100, 150, 255, bid - 64, l);
    else {
        int idx = (bid - 384) * 64 + l;          // WtT[k][g] = W2ihB[g][k]
        if (idx < 60000) {
            int k = idx / 600, g = idx - k * 600;
            WtT[idx] = W2ihB[g * 100 + k];
        }
    }
}

// ---------------------------------------------------------------------------
// Layer 1: K=64 (x k=0, h k=1..50, bias k=63). 1024 thr = 16 waves, one tile
// per wave (tiles 13..15 zero-padded), jj = w*4 + q (< 50).
// out1f layout: u16 fragment tensor [t][blk16][ktx(4)][lane(64)][e(8)].
__global__ __launch_bounds__(1024, 4) void l1_scan(
    const float* __restrict__ x, const uint4* __restrict__ fragF,
    const uint4* __restrict__ fragB, u16* __restrict__ out1f)
{
    const int tid = threadIdx.x;
    const int lane = tid & 63;
    const int w = tid >> 6;           // 0..15 = tile
    const int q = lane >> 4;
    const int b = lane & 15;
    const int blk = blockIdx.x;
    const int dir = blockIdx.y;
    const uint4* frag = dir ? fragB : fragF;

    __shared__ u16 v[2][1024];        // [buf][kt(2)*64 lanes*8 e]
    __shared__ float x_s[128][17];    // padded: conflict-free col reads

    uint4 af0 = frag[(w * 2 + 0) * 64 + lane];
    uint4 af1 = frag[(w * 2 + 1) * 64 + lane];

    const int b0 = blk * 16;
    for (int idx = tid; idx < 1024; idx += 1024) ((u32*)v)[idx] = 0u;
    for (int idx = tid; idx < 2048; idx += 1024) {
        int bb = idx >> 7, t = idx & 127;
        x_s[t][bb] = x[(size_t)(b0 + bb) * TT + t];
    }
    __syncthreads();                  // zero-init complete before special slots
    const u16 oneh = to_h(1.0f);
    if (tid < 16) {
        v[0][(112 + tid) * 8 + 7] = oneh;             // bias row k=63, both bufs
        v[1][(112 + tid) * 8 + 7] = oneh;
        v[0][tid * 8] = to_h(x[(size_t)(b0 + tid) * TT + (dir ? TT - 1 : 0)]);
    }
    const int jj = w * 4 + q;         // valid < 50
    const int k1 = 1 + jj;
    const int vslot = ((k1 >> 5) * 64 + ((k1 & 31) >> 3) * 16 + b) * 8 + (k1 & 7);
    const int k2 = dir * 50 + (jj < 50 ? jj : 0);
    const size_t eb = (((size_t)blk * 4 + (k2 >> 5)) * 64
                       + ((k2 & 31) >> 3) * 16 + b) * 8 + (k2 & 7);
    float c = 0.f;
    __syncthreads();

#define L1_STEP(T, CUR) { \
    uint4 bf0 = *(const uint4*)&v[CUR][lane * 8]; \
    uint4 bf1 = *(const uint4*)&v[CUR][(64 + lane) * 8]; \
    f32x4 acc = (f32x4){0.f, 0.f, 0.f, 0.f}; \
    acc = mfma16(af0, bf0, acc); \
    acc = mfma16(af1, bf1, acc); \
    const int tt = dir ? 127 - (T) : (T); \
    if (jj < 50) { \
        float hn = lstm_cell(acc[0], acc[1], acc[2], acc[3], c); \
        u16 hb = to_h(hn); \
        out1f[eb + (size_t)tt * 131072] = hb; \
        v[1 - (CUR)][vslot] = hb; \
    } \
    if (tid < 16 && (T) < 127) \
        v[1 - (CUR)][tid * 8] = to_h(x_s[dir ? 126 - (T) : (T) + 1][tid]); \
    wg_barrier_lds(); }

    for (int t2 = 0; t2 < TT; t2 += 2) {
        L1_STEP(t2, 0)
        L1_STEP(t2 + 1, 1)
    }
#undef L1_STEP
}

// ---------------------------------------------------------------------------
// Layer 2 forward: K=256 (x k=0..99, h k=100..249, bias k=255). 512 thr = 8
// waves, 5 tiles/wave (tile = w + 8p), jj = tile*4 + q (< 150).
// Step: {5 h-MFMAs(p); cell(p); ds_write} per p (VALU overlaps next p's
// MFMAs), then late x-refill MFMAs from pf(t+1) + x k=96..99 LDS feed.
__global__ __launch_bounds__(512, 2) void l2f_scan(
    const uint4* __restrict__ frag, const u16* __restrict__ out1f,
    float* __restrict__ net)
{
    const int tid = threadIdx.x;
    const int lane = tid & 63;
    const int w = tid >> 6;           // 0..7
    const int q = lane >> 4;
    const int b = lane & 15;
    const int blk = blockIdx.x;
    const int b0 = blk * 16;
    const uint4* o4 = (const uint4*)out1f;

    __shared__ u16 v[2][4096];        // [buf][kt(8)*64 lanes*8 e]

    uint4 af[5][8];
    #pragma unroll
    for (int i = 0; i < 5; ++i)
        #pragma unroll
        for (int kt = 0; kt < 8; ++kt)
            af[i][kt] = frag[((w + 8 * i) * 8 + kt) * 64 + lane];

    for (int idx = tid; idx < 4096; idx += 512) ((u32*)v)[idx] = 0u;

    uint4 pf[4];
    #pragma unroll
    for (int ktx = 0; ktx < 4; ++ktx)
        pf[ktx] = o4[((size_t)blk * 4 + ktx) * 64 + lane];   // x(0)

    __syncthreads();                  // zero-init complete before special slots
    const u16 oneh = to_h(1.0f);
    if (tid < 16) {                   // bias row k=255, both bufs
        v[0][(496 + tid) * 8 + 7] = oneh;
        v[1][(496 + tid) * 8 + 7] = oneh;
    }
    if (w == 0 && lane < 16) {        // x(0) k=96..99 into v[0] kt3 slots
        uint2 xv; xv.x = pf[3].x; xv.y = pf[3].y;
        *(uint2*)&v[0][(192 + lane) * 8] = xv;
    }

    int vslot[5];
    #pragma unroll
    for (int p = 0; p < 5; ++p) {
        int jj = (w + 8 * p) * 4 + q;
        int k = 100 + (jj < 150 ? jj : 0);
        vslot[p] = ((k >> 5) * 64 + ((k & 31) >> 3) * 16 + b) * 8 + (k & 7);
    }
    float c[5] = {0.f, 0.f, 0.f, 0.f, 0.f};

    // Prologue: acc = x-part of gates at t=0 (kt0..2; kt3 x-cols via LDS)
    f32x4 acc[5];
    #pragma unroll
    for (int p = 0; p < 5; ++p) {
        acc[p] = mfma16(af[p][0], pf[0], (f32x4){0.f, 0.f, 0.f, 0.f});
        acc[p] = mfma16(af[p][1], pf[1], acc[p]);
        acc[p] = mfma16(af[p][2], pf[2], acc[p]);
    }
    __syncthreads();

#define L2F_STEP(T, CUR) { \
    uint4 bfu[5]; \
    _Pragma("unroll") for (int kh = 0; kh < 5; ++kh) \
        bfu[kh] = *(const uint4*)&v[CUR][((kh + 3) * 64 + lane) * 8]; \
    const int tn = ((T) < 127) ? (T) + 1 : 127; \
    _Pragma("unroll") for (int ktx = 0; ktx < 4; ++ktx) \
        pf[ktx] = o4[(((size_t)tn * 64 + blk) * 4 + ktx) * 64 + lane]; \
    _Pragma("unroll") for (int p = 0; p < 5; ++p) { \
        _Pragma("unroll") for (int kh = 0; kh < 5; ++kh) \
            acc[p] = mfma16(af[p][kh + 3], bfu[kh], acc[p]); \
        int jj = (w + 8 * p) * 4 + q; \
        if (jj < 150) { \
            float hn = lstm_cell(acc[p][0], acc[p][1], acc[p][2], acc[p][3], c[p]); \
            v[1 - (CUR)][vslot[p]] = to_h(hn); \
            if ((T) == 127) net[(size_t)(b0 + b) * 300 + jj] = hn; \
        } \
    } \
    _Pragma("unroll") for (int p = 0; p < 5; ++p) { \
        acc[p] = mfma16(af[p][0], pf[0], (f32x4){0.f, 0.f, 0.f, 0.f}); \
        acc[p] = mfma16(af[p][1], pf[1], acc[p]); \
        acc[p] = mfma16(af[p][2], pf[2], acc[p]); \
    } \
    if (w == 0 && lane < 16) { \
        uint2 xv; xv.x = pf[3].x; xv.y = pf[3].y; \
        *(uint2*)&v[1 - (CUR)][(192 + lane) * 8] = xv; \
    } \
    wg_barrier_lds(); }

    for (int t2 = 0; t2 < TT; t2 += 2) {
        L2F_STEP(t2, 0)
        L2F_STEP(t2 + 1, 1)
    }
#undef L2F_STEP
}

// ---------------------------------------------------------------------------
// Layer 2 backward = single step from zero state (Whh_b drops out).
__global__ __launch_bounds__(640, 1) void l2b_step(
    const u16* __restrict__ out1f, const float* __restrict__ WtT,
    const float* __restrict__ bias, float* __restrict__ net)   // writes [:, 150:300]
{
    const int tid = threadIdx.x;
    const int blk = blockIdx.x;
    const int b0 = blk * 16;
    __shared__ alignas(16) float x_s[100][16];
    __shared__ alignas(16) float gbuf[16][644];
    for (int idx = tid; idx < 1600; idx += 640) {
        int k2 = idx >> 4, bb = idx & 15;
        x_s[k2][bb] = from_h(out1f[((((size_t)127 * 64 + blk) * 4 + (k2 >> 5)) * 64
                                    + ((k2 & 31) >> 3) * 16 + bb) * 8 + (k2 & 7)]);
    }
    __syncthreads();
    if (tid < 600) {
        int g = tid;
        float acc[16];
        #pragma unroll
        for (int bb = 0; bb < 16; ++bb) acc[bb] = 0.f;
        for (int k = 0; k < 100; ++k) {
            float wv = WtT[k * 600 + g];
            float4 xa = *(const float4*)&x_s[k][0];
            float4 xb = *(const float4*)&x_s[k][4];
            float4 xc = *(const float4*)&x_s[k][8];
            float4 xd = *(const float4*)&x_s[k][12];
            acc[0] = fmaf(wv, xa.x, acc[0]);  acc[1] = fmaf(wv, xa.y, acc[1]);
            acc[2] = fmaf(wv, xa.z, acc[2]);  acc[3] = fmaf(wv, xa.w, acc[3]);
            acc[4] = fmaf(wv, xb.x, acc[4]);  acc[5] = fmaf(wv, xb.y, acc[5]);
            acc[6] = fmaf(wv, xb.z, acc[6]);  acc[7] = fmaf(wv, xb.w, acc[7]);
            acc[8] = fmaf(wv, xc.x, acc[8]);  acc[9] = fmaf(wv, xc.y, acc[9]);
            acc[10] = fmaf(wv, xc.z, acc[10]); acc[11] = fmaf(wv, xc.w, acc[11]);
            acc[12] = fmaf(wv, xd.x, acc[12]); acc[13] = fmaf(wv, xd.y, acc[13]);
            acc[14] = fmaf(wv, xd.z, acc[14]); acc[15] = fmaf(wv, xd.w, acc[15]);
        }
        #pragma unroll
        for (int bb = 0; bb < 16; ++bb) gbuf[bb][g] = acc[bb];
    }
    __syncthreads();
    for (int idx = tid; idx < 2400; idx += 640) {
        int j = idx >> 4, bb = idx & 15;
        float ig = gbuf[bb][j]       + bias[j];
        float gg = gbuf[bb][j + 300] + bias[j + 300];
        float og = gbuf[bb][j + 450] + bias[j + 450];
        float cn = sigm(ig) * tanh_(gg);           // c0 = 0 -> forget term vanishes
        float hn = sigm(og) * tanh_(cn);
        net[(size_t)(b0 + bb) * 300 + 150 + j] = hn;
    }
}

// waveform_feat + pef + pef_logits + feat
__global__ void head1(const float* __restrict__ net, const float* __restrict__ rrs,
                      const float* __restrict__ headW, const float* __restrict__ headb,
                      const float* __restrict__ p1W, const float* __restrict__ p1b,
                      const float* __restrict__ p2W, const float* __restrict__ p2b,
                      float* __restrict__ out)
{
    int gid = blockIdx.x * 256 + threadIdx.x;     // 4096
    int b = gid >> 2, og = gid & 3;
    float acc[5];
    #pragma unroll
    for (int o2 = 0; o2 < 5; ++o2) acc[o2] = headb[og * 5 + o2];
    const float* nb = net + (size_t)b * 300;
    for (int k = 0; k < 300; ++k) {
        float nv = nb[k];
        #pragma unroll
        for (int o2 = 0; o2 < 5; ++o2)
            acc[o2] = fmaf(headW[(og * 5 + o2) * 300 + k], nv, acc[o2]);
    }
    #pragma unroll
    for (int o2 = 0; o2 < 5; ++o2) {
        int o = og * 5 + o2;
        float vv = acc[o2] > 0.f ? acc[o2] : 0.3f * acc[o2];
        out[b * 20 + o] = vv;                  // waveform_feat
        out[22528 + b * 30 + o] = vv;          // feat[:, :20]
    }
    if (og == 0) {
        float p[10];
        #pragma unroll
        for (int r = 0; r < 10; ++r) {
            float a = p1b[r];
            #pragma unroll
            for (int qq = 0; qq < 4; ++qq) a = fmaf(p1W[r * 4 + qq], rrs[b * 4 + qq], a);
            p[r] = a > 0.f ? a : 0.3f * a;
            out[22528 + b * 30 + 20 + r] = p[r];   // feat[:, 20:30]
        }
        #pragma unroll
        for (int s = 0; s < 2; ++s) {
            float a = p2b[s];
            #pragma unroll
            for (int r = 0; r < 10; ++r) a = fmaf(p2W[s * 10 + r], p[r], a);
            out[20480 + b * 2 + s] = a;            // pef_logits
        }
    }
}

__global__ void head2(const float* __restrict__ fcW, const float* __restrict__ fcb,
                      float* __restrict__ out)
{
    int b = blockIdx.x * 256 + threadIdx.x;   // 1024
    const float* feat = out + 22528 + b * 30;
    float f[30];
    #pragma unroll
    for (int k = 0; k < 30; ++k) f[k] = feat[k];
    #pragma unroll
    for (int s = 0; s < 4; ++s) {
        float a = fcb[s];
        #pragma unroll
        for (int k = 0; k < 30; ++k) a = fmaf(fcW[s * 30 + k], f[k], a);
        out[53248 + b * 4 + s] = a;
    }
}

extern "C" void kernel_launch(void* const* d_in, const int* in_sizes, int n_in,
                              void* d_out, int out_size, void* d_ws, size_t ws_size,
                              hipStream_t stream)
{
    const float* x     = (const float*)d_in[0];
    const float* rrs   = (const float*)d_in[1];
    const float* W1ihF = (const float*)d_in[2];
    const float* W1hhF = (const float*)d_in[3];
    const float* b1F   = (const float*)d_in[4];
    const float* W1ihB = (const float*)d_in[5];
    const float* W1hhB = (const float*)d_in[6];
    const float* b1B   = (const float*)d_in[7];
    const float* W2ihF = (const float*)d_in[8];
    const float* W2hhF = (const float*)d_in[9];
    const float* b2F   = (const float*)d_in[10];
    const float* W2ihB = (const float*)d_in[11];
    // d_in[12] (l2_Whh_b) unused: backward output at t=T-1 starts from h0=0.
    const float* b2B   = (const float*)d_in[13];
    const float* headW = (const float*)d_in[14];
    const float* headb = (const float*)d_in[15];
    const float* p1W   = (const float*)d_in[16];
    const float* p1b   = (const float*)d_in[17];
    const float* p2W   = (const float*)d_in[18];
    const float* p2b   = (const float*)d_in[19];
    const float* fcW   = (const float*)d_in[20];
    const float* fcb   = (const float*)d_in[21];
    float* out = (float*)d_out;

    char* ws = (char*)d_ws;
    uint4* frag1f = (uint4*)(ws + 0);          //  32 KB (16 tiles x 2 kt)
    uint4* frag1b = (uint4*)(ws + 32768);      //  32 KB
    uint4* frag2f = (uint4*)(ws + 65536);      // 320 KB (40 tiles x 8 kt)
    float* WtT    = (float*)(ws + 393216);     // 240 KB (Wih2_b^T [100][600])
    u16*   out1f  = (u16*)(ws + 655360);       //  32 MB ([128][64][4][64][8] u16)
    float* net    = (float*)(ws + 655360 + 33554432);  // 1.2 MB ([1024][300])
    (void)ws_size; (void)in_sizes; (void)n_in; (void)out_size;

    prep_all<<<1322, 64, 0, stream>>>(W1ihF, W1hhF, b1F, W1ihB, W1hhB, b1B,
                                      W2ihF, W2hhF, b2F, W2ihB,
                                      frag1f, frag1b, frag2f, WtT);
    l1_scan<<<dim3(64, 2), 1024, 0, stream>>>(x, frag1f, frag1b, out1f);
    l2f_scan<<<64, 512, 0, stream>>>(frag2f, out1f, net);
    l2b_step<<<64, 640, 0, stream>>>(out1f, WtT, b2B, net);
    head1<<<16, 256, 0, stream>>>(net, rrs, headW, headb, p1W, p1b, p2W, p2b, out);
    head2<<<4, 256, 0, stream>>>(fcW, fcb, out);
}

// Round 10
// 280.755 us; speedup vs baseline: 2.3007x; 1.0348x over previous
//
#include <hip/hip_runtime.h>

// BiLSTM on MI355X.
//  - l2f_scan (r10): per step — issue bfu ds_reads, hide their latency under
//    the 15 x-part MFMAs (register-only), depth-2 x prefetch (pfA/pfB, 2-step
//    cover -> no vmcnt stall), kh-major h-MFMAs (perfect pipelining) with
//    per-p cell tail. One raw lgkmcnt-only barrier per step.
//  - l1_scan: 512 thr (8 waves x 2 tiles), same read-first ordering.
//  - l2b: backward scan's last output = single step from zero state.
//  - bias folded as an extra K-column against a constant-1.0 B row.
//  - Fused LSTM cell: 5 exp2 + 2 rcp, clamps only on tanh args.

typedef unsigned short u16;
typedef unsigned int u32;
typedef float f32x4 __attribute__((ext_vector_type(4)));
typedef _Float16 f16x8 __attribute__((ext_vector_type(8)));
typedef short s16x8 __attribute__((ext_vector_type(8)));

#if __has_builtin(__builtin_amdgcn_mfma_f32_16x16x32_f16)
#define USE_F16 1
#else
#define USE_F16 0
#endif

#define B1 1024
#define TT 128

__device__ __forceinline__ u16 to_h(float x) {
#if USE_F16
    _Float16 h = (_Float16)x;
    return __builtin_bit_cast(u16, h);
#else
    u32 u = __builtin_bit_cast(u32, x);
    u32 r = u + 0x7FFFu + ((u >> 16) & 1u);
    return (u16)(r >> 16);
#endif
}
__device__ __forceinline__ float from_h(u16 s) {
#if USE_F16
    return (float)__builtin_bit_cast(_Float16, s);
#else
    u32 u = ((u32)s) << 16;
    return __builtin_bit_cast(float, u);
#endif
}

__device__ __forceinline__ f32x4 mfma16(uint4 a, uint4 b, f32x4 c) {
#if USE_F16
    return __builtin_amdgcn_mfma_f32_16x16x32_f16(
        __builtin_bit_cast(f16x8, a), __builtin_bit_cast(f16x8, b), c, 0, 0, 0);
#else
    return __builtin_amdgcn_mfma_f32_16x16x32_bf16(
        __builtin_bit_cast(s16x8, a), __builtin_bit_cast(s16x8, b), c, 0, 0, 0);
#endif
}

#define LOG2E 1.4426950408889634f
__device__ __forceinline__ float sigm(float x) {
    return __builtin_amdgcn_rcpf(1.f + __builtin_amdgcn_exp2f(-LOG2E * x));
}
__device__ __forceinline__ float tanh_(float x) {
    return 1.f - 2.f * __builtin_amdgcn_rcpf(1.f + __builtin_amdgcn_exp2f(2.f * LOG2E * x));
}
__device__ __forceinline__ float clampf(float x, float k) {
    return fminf(fmaxf(x, -k), k);    // -> v_med3_f32
}

// Fused LSTM cell: c' = sigm(f)*c + sigm(i)*tanh(g); h = sigm(o)*tanh(c').
// Shared-denominator form: 5 exp2 + 2 rcp. Clamps only where the doubled
// exponent can overflow f32 (g, c'); sigmoid-path exp2 is finite for |x|<80.
__device__ __forceinline__ float lstm_cell(float ig, float fg, float gg, float og,
                                           float& c)
{
    float ei = __builtin_amdgcn_exp2f(-LOG2E * ig);
    float ef = __builtin_amdgcn_exp2f(-LOG2E * fg);
    float eg = __builtin_amdgcn_exp2f(2.f * LOG2E * clampf(gg, 15.f));
    float P   = (1.f + ei) * (eg + 1.f);
    float num = fmaf(c, P, (eg - 1.f) * (1.f + ef));
    float cn  = num * __builtin_amdgcn_rcpf((1.f + ef) * P);
    c = cn;
    float eo = __builtin_amdgcn_exp2f(-LOG2E * og);
    float ec = __builtin_amdgcn_exp2f(2.f * LOG2E * clampf(cn, 15.f));
    return (ec - 1.f) * __builtin_amdgcn_rcpf((1.f + eo) * (ec + 1.f));
}

// Raw workgroup barrier: waits only LDS ops (lgkmcnt); global loads/stores
// stay in flight across it (compiler inserts counted vmcnt at register uses).
__device__ __forceinline__ void wg_barrier_lds() {
    __builtin_amdgcn_sched_barrier(0);
    asm volatile("s_waitcnt lgkmcnt(0)" ::: "memory");
    __builtin_amdgcn_s_barrier();
    __builtin_amdgcn_sched_barrier(0);
}

// ---------------------------------------------------------------------------
// Weight packing [Wih | Whh | bias-col | 0] into MFMA A-fragments, permuted:
// tile row m = q*4 + tau maps to original weight row tau*GR + (tile*4 + q).
__device__ __forceinline__ void prep_frag_body(
    const float* __restrict__ Wih, const float* __restrict__ Whh,
    const float* __restrict__ bias, uint4* __restrict__ dst,
    int GR, int KT, int x_off, int x_len, int h_off, int h_len, int bias_k,
    int bid, int l)
{
    int tile = bid / KT, kt = bid - tile * KT;
    int ml = l & 15;
    int qq = ml >> 2, tau = ml & 3;
    int jj = tile * 4 + qq;
    bool valid = jj < GR;
    int row = tau * GR + jj;
    u32 dw[4];
    #pragma unroll
    for (int d = 0; d < 4; ++d) {
        u16 hh[2];
        #pragma unroll
        for (int s = 0; s < 2; ++s) {
            int j = d * 2 + s;
            int k = kt * 32 + (l >> 4) * 8 + j;
            float val = 0.f;
            if (valid) {
                if (k >= x_off && k < x_off + x_len) val = Wih[row * x_len + (k - x_off)];
                else if (k >= h_off && k < h_off + h_len) val = Whh[row * h_len + (k - h_off)];
                else if (k == bias_k) val = bias[row];
            }
            hh[s] = to_h(val);
        }
        dw[d] = (u32)hh[0] | ((u32)hh[1] << 16);
    }
    uint4 o; o.x = dw[0]; o.y = dw[1]; o.z = dw[2]; o.w = dw[3];
    dst[bid * 64 + l] = o;
}

__global__ void prep_all(const float* __restrict__ W1ihF, const float* __restrict__ W1hhF,
                         const float* __restrict__ b1F,
                         const float* __restrict__ W1ihB, const float* __restrict__ W1hhB,
                         const float* __restrict__ b1B,
                         const float* __restrict__ W2ihF, const float* __restrict__ W2hhF,
                         const float* __restrict__ b2F, const float* __restrict__ W2ihB,
                         uint4* __restrict__ frag1f, uint4* __restrict__ frag1b,
                         uint4* __restrict__ frag2f, float* __restrict__ WtT)
{
    int bid = blockIdx.x;
    int l = threadIdx.x;
    if (bid < 32)
        prep_frag_body(W1ihF, W1hhF, b1F, frag1f, 50, 2, 0, 1, 1, 50, 63, bid, l);
    else if (bid < 64)
        prep_frag_body(W1ihB, W1hhB, b1B, frag1b, 50, 2, 0, 1, 1, 50, 63, bid - 32, l);
    else if (bid < 384)
        prep_frag_body(W2ihF, W2hhF, b2F, frag2f, 150, 8, 0, 100, 100, 150, 255, bid - 64, l);
    else {
        int idx = (bid - 384) * 64 + l;          // WtT[k][g] = W2ihB[g][k]
        if (idx < 60000) {
            int k = idx / 600, g = idx - k * 600;
            WtT[idx] = W2ihB[g * 100 + k];
        }
    }
}

// ---------------------------------------------------------------------------
// Layer 1: K=64 (x k=0, h k=1..50, bias k=63). 512 thr = 8 waves, 2 tiles per
// wave (tile = w, w+8; tiles 13..15 zero), jj = tile*4 + q (< 50).
// out1f layout: u16 fragment tensor [t][blk16][ktx(4)][lane(64)][e(8)].
__global__ __launch_bounds__(512, 2) void l1_scan(
    const float* __restrict__ x, const uint4* __restrict__ fragF,
    const uint4* __restrict__ fragB, u16* __restrict__ out1f)
{
    const int tid = threadIdx.x;
    const int lane = tid & 63;
    const int w = tid >> 6;           // 0..7
    const int q = lane >> 4;
    const int b = lane & 15;
    const int blk = blockIdx.x;
    const int dir = blockIdx.y;
    const uint4* frag = dir ? fragB : fragF;

    __shared__ u16 v[2][1024];        // [buf][kt(2)*64 lanes*8 e]
    __shared__ float x_s[128][17];    // padded: conflict-free col reads

    uint4 af[2][2];
    #pragma unroll
    for (int p = 0; p < 2; ++p)
        #pragma unroll
        for (int kt = 0; kt < 2; ++kt)
            af[p][kt] = frag[((w + 8 * p) * 2 + kt) * 64 + lane];

    const int b0 = blk * 16;
    for (int idx = tid; idx < 1024; idx += 512) ((u32*)v)[idx] = 0u;
    for (int idx = tid; idx < 2048; idx += 512) {
        int bb = idx >> 7, t = idx & 127;
        x_s[t][bb] = x[(size_t)(b0 + bb) * TT + t];
    }
    __syncthreads();                  // zero-init complete before special slots
    const u16 oneh = to_h(1.0f);
    if (tid < 16) {
        v[0][(112 + tid) * 8 + 7] = oneh;             // bias row k=63, both bufs
        v[1][(112 + tid) * 8 + 7] = oneh;
        v[0][tid * 8] = to_h(x[(size_t)(b0 + tid) * TT + (dir ? TT - 1 : 0)]);
    }
    int vslot[2]; size_t eb[2];
    #pragma unroll
    for (int p = 0; p < 2; ++p) {
        int jj = (w + 8 * p) * 4 + q;
        int k1 = 1 + (jj < 50 ? jj : 0);
        vslot[p] = ((k1 >> 5) * 64 + ((k1 & 31) >> 3) * 16 + b) * 8 + (k1 & 7);
        int k2 = dir * 50 + (jj < 50 ? jj : 0);
        eb[p] = (((size_t)blk * 4 + (k2 >> 5)) * 64
                 + ((k2 & 31) >> 3) * 16 + b) * 8 + (k2 & 7);
    }
    float c[2] = {0.f, 0.f};
    __syncthreads();

#define L1_STEP(T, CUR) { \
    uint4 bf0 = *(const uint4*)&v[CUR][lane * 8]; \
    uint4 bf1 = *(const uint4*)&v[CUR][(64 + lane) * 8]; \
    f32x4 acc[2]; \
    _Pragma("unroll") for (int p = 0; p < 2; ++p) { \
        acc[p] = mfma16(af[p][0], bf0, (f32x4){0.f, 0.f, 0.f, 0.f}); \
        acc[p] = mfma16(af[p][1], bf1, acc[p]); \
    } \
    const int tt = dir ? 127 - (T) : (T); \
    _Pragma("unroll") for (int p = 0; p < 2; ++p) { \
        int jj = (w + 8 * p) * 4 + q; \
        if (jj < 50) { \
            float hn = lstm_cell(acc[p][0], acc[p][1], acc[p][2], acc[p][3], c[p]); \
            u16 hb = to_h(hn); \
            out1f[eb[p] + (size_t)tt * 131072] = hb; \
            v[1 - (CUR)][vslot[p]] = hb; \
        } \
    } \
    if (tid < 16 && (T) < 127) \
        v[1 - (CUR)][tid * 8] = to_h(x_s[dir ? 126 - (T) : (T) + 1][tid]); \
    wg_barrier_lds(); }

    for (int t2 = 0; t2 < TT; t2 += 2) {
        L1_STEP(t2, 0)
        L1_STEP(t2 + 1, 1)
    }
#undef L1_STEP
}

// ---------------------------------------------------------------------------
// Layer 2 forward: K=256 (x k=0..99, h k=100..249, bias k=255). 512 thr = 8
// waves, 5 tiles/wave (tile = w + 8p), jj = tile*4 + q (< 150).
// Step: issue bfu ds_reads; 15 x-MFMAs from pf (hide LDS latency); issue
// x(t+2) loads (depth-2 prefetch, never stalls); kh-major h-MFMAs (kh=0..3),
// per-p tail {kh=4 MFMA; cell; ds_write}. One lgkmcnt-only barrier per step.
__global__ __launch_bounds__(512, 2) void l2f_scan(
    const uint4* __restrict__ frag, const u16* __restrict__ out1f,
    float* __restrict__ net)
{
    const int tid = threadIdx.x;
    const int lane = tid & 63;
    const int w = tid >> 6;           // 0..7
    const int q = lane >> 4;
    const int b = lane & 15;
    const int blk = blockIdx.x;
    const int b0 = blk * 16;
    const uint4* o4 = (const uint4*)out1f;

    __shared__ u16 v[2][4096];        // [buf][kt(8)*64 lanes*8 e]

    uint4 af[5][8];
    #pragma unroll
    for (int i = 0; i < 5; ++i)
        #pragma unroll
        for (int kt = 0; kt < 8; ++kt)
            af[i][kt] = frag[((w + 8 * i) * 8 + kt) * 64 + lane];

    for (int idx = tid; idx < 4096; idx += 512) ((u32*)v)[idx] = 0u;

    uint4 pfA[4], pfB[4];             // x(t), x(t+1) — depth-2 prefetch
    #pragma unroll
    for (int ktx = 0; ktx < 4; ++ktx) {
        pfA[ktx] = o4[((size_t)(0 * 64 + blk) * 4 + ktx) * 64 + lane];   // x(0)
        pfB[ktx] = o4[((size_t)(1 * 64 + blk) * 4 + ktx) * 64 + lane];   // x(1)
    }

    __syncthreads();                  // zero-init complete before special slots
    const u16 oneh = to_h(1.0f);
    if (tid < 16) {                   // bias row k=255, both bufs
        v[0][(496 + tid) * 8 + 7] = oneh;
        v[1][(496 + tid) * 8 + 7] = oneh;
    }
    if (w == 0 && lane < 16) {        // x(0) k=96..99 into v[0] kt3 slots
        uint2 xv; xv.x = pfA[3].x; xv.y = pfA[3].y;
        *(uint2*)&v[0][(192 + lane) * 8] = xv;
    }

    int vslot[5];
    #pragma unroll
    for (int p = 0; p < 5; ++p) {
        int jj = (w + 8 * p) * 4 + q;
        int k = 100 + (jj < 150 ? jj : 0);
        vslot[p] = ((k >> 5) * 64 + ((k & 31) >> 3) * 16 + b) * 8 + (k & 7);
    }
    float c[5] = {0.f, 0.f, 0.f, 0.f, 0.f};
    __syncthreads();

// Step T: PFC holds x(T) (2 steps old), PFD holds x(T+1) (1 step old).
// PFC regs are refilled with x(T+2) after consumption.
#define L2F_STEP(T, CUR, PFC, PFD) { \
    uint4 bfu[5]; \
    _Pragma("unroll") for (int kh = 0; kh < 5; ++kh) \
        bfu[kh] = *(const uint4*)&v[CUR][((kh + 3) * 64 + lane) * 8]; \
    f32x4 acc[5]; \
    _Pragma("unroll") for (int p = 0; p < 5; ++p) { \
        acc[p] = mfma16(af[p][0], PFC[0], (f32x4){0.f, 0.f, 0.f, 0.f}); \
        acc[p] = mfma16(af[p][1], PFC[1], acc[p]); \
        acc[p] = mfma16(af[p][2], PFC[2], acc[p]); \
    } \
    const int tn = ((T) < 126) ? (T) + 2 : 127; \
    _Pragma("unroll") for (int ktx = 0; ktx < 4; ++ktx) \
        PFC[ktx] = o4[(((size_t)tn * 64 + blk) * 4 + ktx) * 64 + lane]; \
    _Pragma("unroll") for (int kh = 0; kh < 4; ++kh) { \
        _Pragma("unroll") for (int p = 0; p < 5; ++p) \
            acc[p] = mfma16(af[p][kh + 3], bfu[kh], acc[p]); \
    } \
    _Pragma("unroll") for (int p = 0; p < 5; ++p) { \
        acc[p] = mfma16(af[p][7], bfu[4], acc[p]); \
        int jj = (w + 8 * p) * 4 + q; \
        if (jj < 150) { \
            float hn = lstm_cell(acc[p][0], acc[p][1], acc[p][2], acc[p][3], c[p]); \
            v[1 - (CUR)][vslot[p]] = to_h(hn); \
            if ((T) == 127) net[(size_t)(b0 + b) * 300 + jj] = hn; \
        } \
    } \
    if (w == 0 && lane < 16) { \
        uint2 xv; xv.x = PFD[3].x; xv.y = PFD[3].y; \
        *(uint2*)&v[1 - (CUR)][(192 + lane) * 8] = xv; \
    } \
    wg_barrier_lds(); }

    for (int t2 = 0; t2 < TT; t2 += 2) {
        L2F_STEP(t2, 0, pfA, pfB)
        L2F_STEP(t2 + 1, 1, pfB, pfA)
    }
#undef L2F_STEP
}

// ---------------------------------------------------------------------------
// Layer 2 backward = single step from zero state (Whh_b drops out).
__global__ __launch_bounds__(640, 1) void l2b_step(
    const u16* __restrict__ out1f, const float* __restrict__ WtT,
    const float* __restrict__ bias, float* __restrict__ net)   // writes [:, 150:300]
{
    const int tid = threadIdx.x;
    const int blk = blockIdx.x;
    const int b0 = blk * 16;
    __shared__ alignas(16) float x_s[100][16];
    __shared__ alignas(16) float gbuf[16][644];
    for (int idx = tid; idx < 1600; idx += 640) {
        int k2 = idx >> 4, bb = idx & 15;
        x_s[k2][bb] = from_h(out1f[((((size_t)127 * 64 + blk) * 4 + (k2 >> 5)) * 64
                                    + ((k2 & 31) >> 3) * 16 + bb) * 8 + (k2 & 7)]);
    }
    __syncthreads();
    if (tid < 600) {
        int g = tid;
        float acc[16];
        #pragma unroll
        for (int bb = 0; bb < 16; ++bb) acc[bb] = 0.f;
        for (int k = 0; k < 100; ++k) {
            float wv = WtT[k * 600 + g];
            float4 xa = *(const float4*)&x_s[k][0];
            float4 xb = *(const float4*)&x_s[k][4];
            float4 xc = *(const float4*)&x_s[k][8];
            float4 xd = *(const float4*)&x_s[k][12];
            acc[0] = fmaf(wv, xa.x, acc[0]);  acc[1] = fmaf(wv, xa.y, acc[1]);
            acc[2] = fmaf(wv, xa.z, acc[2]);  acc[3] = fmaf(wv, xa.w, acc[3]);
            acc[4] = fmaf(wv, xb.x, acc[4]);  acc[5] = fmaf(wv, xb.y, acc[5]);
            acc[6] = fmaf(wv, xb.z, acc[6]);  acc[7] = fmaf(wv, xb.w, acc[7]);
            acc[8] = fmaf(wv, xc.x, acc[8]);  acc[9] = fmaf(wv, xc.y, acc[9]);
            acc[10] = fmaf(wv, xc.z, acc[10]); acc[11] = fmaf(wv, xc.w, acc[11]);
            acc[12] = fmaf(wv, xd.x, acc[12]); acc[13] = fmaf(wv, xd.y, acc[13]);
            acc[14] = fmaf(wv, xd.z, acc[14]); acc[15] = fmaf(wv, xd.w, acc[15]);
        }
        #pragma unroll
        for (int bb = 0; bb < 16; ++bb) gbuf[bb][g] = acc[bb];
    }
    __syncthreads();
    for (int idx = tid; idx < 2400; idx += 640) {
        int j = idx >> 4, bb = idx & 15;
        float ig = gbuf[bb][j]       + bias[j];
        float gg = gbuf[bb][j + 300] + bias[j + 300];
        float og = gbuf[bb][j + 450] + bias[j + 450];
        float cn = sigm(ig) * tanh_(gg);           // c0 = 0 -> forget term vanishes
        float hn = sigm(og) * tanh_(cn);
        net[(size_t)(b0 + bb) * 300 + 150 + j] = hn;
    }
}

// waveform_feat + pef + pef_logits + feat
__global__ void head1(const float* __restrict__ net, const float* __restrict__ rrs,
                      const float* __restrict__ headW, const float* __restrict__ headb,
                      const float* __restrict__ p1W, const float* __restrict__ p1b,
                      const float* __restrict__ p2W, const float* __restrict__ p2b,
                      float* __restrict__ out)
{
    int gid = blockIdx.x * 256 + threadIdx.x;     // 4096
    int b = gid >> 2, og = gid & 3;
    float acc[5];
    #pragma unroll
    for (int o2 = 0; o2 < 5; ++o2) acc[o2] = headb[og * 5 + o2];
    const float* nb = net + (size_t)b * 300;
    for (int k = 0; k < 300; ++k) {
        float nv = nb[k];
        #pragma unroll
        for (int o2 = 0; o2 < 5; ++o2)
            acc[o2] = fmaf(headW[(og * 5 + o2) * 300 + k], nv, acc[o2]);
    }
    #pragma unroll
    for (int o2 = 0; o2 < 5; ++o2) {
        int o = og * 5 + o2;
        float vv = acc[o2] > 0.f ? acc[o2] : 0.3f * acc[o2];
        out[b * 20 + o] = vv;                  // waveform_feat
        out[22528 + b * 30 + o] = vv;          // feat[:, :20]
    }
    if (og == 0) {
        float p[10];
        #pragma unroll
        for (int r = 0; r < 10; ++r) {
            float a = p1b[r];
            #pragma unroll
            for (int qq = 0; qq < 4; ++qq) a = fmaf(p1W[r * 4 + qq], rrs[b * 4 + qq], a);
            p[r] = a > 0.f ? a : 0.3f * a;
            out[22528 + b * 30 + 20 + r] = p[r];   // feat[:, 20:30]
        }
        #pragma unroll
        for (int s = 0; s < 2; ++s) {
            float a = p2b[s];
            #pragma unroll
            for (int r = 0; r < 10; ++r) a = fmaf(p2W[s * 10 + r], p[r], a);
            out[20480 + b * 2 + s] = a;            // pef_logits
        }
    }
}

__global__ void head2(const float* __restrict__ fcW, const float* __restrict__ fcb,
                      float* __restrict__ out)
{
    int b = blockIdx.x * 256 + threadIdx.x;   // 1024
    const float* feat = out + 22528 + b * 30;
    float f[30];
    #pragma unroll
    for (int k = 0; k < 30; ++k) f[k] = feat[k];
    #pragma unroll
    for (int s = 0; s < 4; ++s) {
        float a = fcb[s];
        #pragma unroll
        for (int k = 0; k < 30; ++k) a = fmaf(fcW[s * 30 + k], f[k], a);
        out[53248 + b * 4 + s] = a;
    }
}

extern "C" void kernel_launch(void* const* d_in, const int* in_sizes, int n_in,
                              void* d_out, int out_size, void* d_ws, size_t ws_size,
                              hipStream_t stream)
{
    const float* x     = (const float*)d_in[0];
    const float* rrs   = (const float*)d_in[1];
    const float* W1ihF = (const float*)d_in[2];
    const float* W1hhF = (const float*)d_in[3];
    const float* b1F   = (const float*)d_in[4];
    const float* W1ihB = (const float*)d_in[5];
    const float* W1hhB = (const float*)d_in[6];
    const float* b1B   = (const float*)d_in[7];
    const float* W2ihF = (const float*)d_in[8];
    const float* W2hhF = (const float*)d_in[9];
    const float* b2F   = (const float*)d_in[10];
    const float* W2ihB = (const float*)d_in[11];
    // d_in[12] (l2_Whh_b) unused: backward output at t=T-1 starts from h0=0.
    const float* b2B   = (const float*)d_in[13];
    const float* headW = (const float*)d_in[14];
    const float* headb = (const float*)d_in[15];
    const float* p1W   = (const float*)d_in[16];
    const float* p1b   = (const float*)d_in[17];
    const float* p2W   = (const float*)d_in[18];
    const float* p2b   = (const float*)d_in[19];
    const float* fcW   = (const float*)d_in[20];
    const float* fcb   = (const float*)d_in[21];
    float* out = (float*)d_out;

    char* ws = (char*)d_ws;
    uint4* frag1f = (uint4*)(ws + 0);          //  32 KB (16 tiles x 2 kt)
    uint4* frag1b = (uint4*)(ws + 32768);      //  32 KB
    uint4* frag2f = (uint4*)(ws + 65536);      // 320 KB (40 tiles x 8 kt)
    float* WtT    = (float*)(ws + 393216);     // 240 KB (Wih2_b^T [100][600])
    u16*   out1f  = (u16*)(ws + 655360);       //  32 MB ([128][64][4][64][8] u16)
    float* net    = (float*)(ws + 655360 + 33554432);  // 1.2 MB ([1024][300])
    (void)ws_size; (void)in_sizes; (void)n_in; (void)out_size;

    prep_all<<<1322, 64, 0, stream>>>(W1ihF, W1hhF, b1F, W1ihB, W1hhB, b1B,
                                      W2ihF, W2hhF, b2F, W2ihB,
                                      frag1f, frag1b, frag2f, WtT);
    l1_scan<<<dim3(64, 2), 512, 0, stream>>>(x, frag1f, frag1b, out1f);
    l2f_scan<<<64, 512, 0, stream>>>(frag2f, out1f, net);
    l2b_step<<<64, 640, 0, stream>>>(out1f, WtT, b2B, net);
    head1<<<16, 256, 0, stream>>>(net, rrs, headW, headb, p1W, p1b, p2W, p2b, out);
    head2<<<4, 256, 0, stream>>>(fcW, fcb, out);
}

// Round 11
// 274.473 us; speedup vs baseline: 2.3534x; 1.0229x over previous
//
#include <hip/hip_runtime.h>

// BiLSTM on MI355X.
//  - l2f_scan (r11): accumulator double-buffer — cells(t) and the 15 x-part
//    MFMAs for t+1 live in ONE scheduling region (VALU/trans ∥ MFMA pipe);
//    loop-carried prefetch pointer (imm offsets); depth-2 x prefetch.
//  - Weights pre-scaled by LOG2E (2·LOG2E for g-gate rows, bias col incl.)
//    so exp2 args come straight from the MFMA: -4 v_mul per cell.
//  - l1_scan: 512 thr (8 waves x 2 tiles), barrier-locked double-buffer.
//  - l2b: backward scan's last output = single step from zero state
//    (unscaled weights, classic sigmoid/tanh path).
//  - One raw lgkmcnt-only barrier per scan step.

typedef unsigned short u16;
typedef unsigned int u32;
typedef float f32x4 __attribute__((ext_vector_type(4)));
typedef _Float16 f16x8 __attribute__((ext_vector_type(8)));
typedef short s16x8 __attribute__((ext_vector_type(8)));

#if __has_builtin(__builtin_amdgcn_mfma_f32_16x16x32_f16)
#define USE_F16 1
#else
#define USE_F16 0
#endif

#define B1 1024
#define TT 128

__device__ __forceinline__ u16 to_h(float x) {
#if USE_F16
    _Float16 h = (_Float16)x;
    return __builtin_bit_cast(u16, h);
#else
    u32 u = __builtin_bit_cast(u32, x);
    u32 r = u + 0x7FFFu + ((u >> 16) & 1u);
    return (u16)(r >> 16);
#endif
}
__device__ __forceinline__ float from_h(u16 s) {
#if USE_F16
    return (float)__builtin_bit_cast(_Float16, s);
#else
    u32 u = ((u32)s) << 16;
    return __builtin_bit_cast(float, u);
#endif
}

__device__ __forceinline__ f32x4 mfma16(uint4 a, uint4 b, f32x4 c) {
#if USE_F16
    return __builtin_amdgcn_mfma_f32_16x16x32_f16(
        __builtin_bit_cast(f16x8, a), __builtin_bit_cast(f16x8, b), c, 0, 0, 0);
#else
    return __builtin_amdgcn_mfma_f32_16x16x32_bf16(
        __builtin_bit_cast(s16x8, a), __builtin_bit_cast(s16x8, b), c, 0, 0, 0);
#endif
}

#define LOG2E 1.4426950408889634f
__device__ __forceinline__ float sigm(float x) {
    return __builtin_amdgcn_rcpf(1.f + __builtin_amdgcn_exp2f(-LOG2E * x));
}
__device__ __forceinline__ float tanh_(float x) {
    return 1.f - 2.f * __builtin_amdgcn_rcpf(1.f + __builtin_amdgcn_exp2f(2.f * LOG2E * x));
}
__device__ __forceinline__ float clampf(float x, float k) {
    return fminf(fmaxf(x, -k), k);    // -> v_med3_f32
}

// Fused LSTM cell, log2-domain gates: inputs are LOG2E*(i,f,o) and
// 2*LOG2E*g (weights pre-scaled at pack time). 5 exp2 + 2 rcp, ~16 VALU.
// Clamp only where the exponent can overflow f32 (g: |43.3| ~ natural 15;
// c': natural 15). c' = sigm(f)c + sigm(i)tanh(g); h = sigm(o)tanh(c').
__device__ __forceinline__ float lstm_cell(float ig2, float fg2, float gg2,
                                           float og2, float& c)
{
    float ei = __builtin_amdgcn_exp2f(-ig2);
    float ef = __builtin_amdgcn_exp2f(-fg2);
    float eg = __builtin_amdgcn_exp2f(clampf(gg2, 43.28f));
    float P   = (1.f + ei) * (eg + 1.f);
    float num = fmaf(c, P, (eg - 1.f) * (1.f + ef));
    float cn  = num * __builtin_amdgcn_rcpf((1.f + ef) * P);
    c = cn;
    float eo = __builtin_amdgcn_exp2f(-og2);
    float ec = __builtin_amdgcn_exp2f(2.f * LOG2E * clampf(cn, 15.f));
    return (ec - 1.f) * __builtin_amdgcn_rcpf((1.f + eo) * (ec + 1.f));
}

// Raw workgroup barrier: waits only LDS ops (lgkmcnt); global loads/stores
// stay in flight across it (compiler inserts counted vmcnt at register uses).
__device__ __forceinline__ void wg_barrier_lds() {
    __builtin_amdgcn_sched_barrier(0);
    asm volatile("s_waitcnt lgkmcnt(0)" ::: "memory");
    __builtin_amdgcn_s_barrier();
    __builtin_amdgcn_sched_barrier(0);
}

// ---------------------------------------------------------------------------
// Weight packing [Wih | Whh | bias-col | 0] into MFMA A-fragments, permuted:
// tile row m = q*4 + tau maps to original weight row tau*GR + (tile*4 + q).
// Rows scaled by LOG2E (tau!=2) / 2*LOG2E (tau==2, the g gate) for exp2 cells.
__device__ __forceinline__ void prep_frag_body(
    const float* __restrict__ Wih, const float* __restrict__ Whh,
    const float* __restrict__ bias, uint4* __restrict__ dst,
    int GR, int KT, int x_off, int x_len, int h_off, int h_len, int bias_k,
    int bid, int l)
{
    int tile = bid / KT, kt = bid - tile * KT;
    int ml = l & 15;
    int qq = ml >> 2, tau = ml & 3;
    int jj = tile * 4 + qq;
    bool valid = jj < GR;
    int row = tau * GR + jj;
    float rowscale = (tau == 2) ? 2.0f * LOG2E : LOG2E;
    u32 dw[4];
    #pragma unroll
    for (int d = 0; d < 4; ++d) {
        u16 hh[2];
        #pragma unroll
        for (int s = 0; s < 2; ++s) {
            int j = d * 2 + s;
            int k = kt * 32 + (l >> 4) * 8 + j;
            float val = 0.f;
            if (valid) {
                if (k >= x_off && k < x_off + x_len) val = Wih[row * x_len + (k - x_off)];
                else if (k >= h_off && k < h_off + h_len) val = Whh[row * h_len + (k - h_off)];
                else if (k == bias_k) val = bias[row];
            }
            hh[s] = to_h(val * rowscale);
        }
        dw[d] = (u32)hh[0] | ((u32)hh[1] << 16);
    }
    uint4 o; o.x = dw[0]; o.y = dw[1]; o.z = dw[2]; o.w = dw[3];
    dst[bid * 64 + l] = o;
}

__global__ void prep_all(const float* __restrict__ W1ihF, const float* __restrict__ W1hhF,
                         const float* __restrict__ b1F,
                         const float* __restrict__ W1ihB, const float* __restrict__ W1hhB,
                         const float* __restrict__ b1B,
                         const float* __restrict__ W2ihF, const float* __restrict__ W2hhF,
                         const float* __restrict__ b2F, const float* __restrict__ W2ihB,
                         uint4* __restrict__ frag1f, uint4* __restrict__ frag1b,
                         uint4* __restrict__ frag2f, float* __restrict__ WtT)
{
    int bid = blockIdx.x;
    int l = threadIdx.x;
    if (bid < 32)
        prep_frag_body(W1ihF, W1hhF, b1F, frag1f, 50, 2, 0, 1, 1, 50, 63, bid, l);
    else if (bid < 64)
        prep_frag_body(W1ihB, W1hhB, b1B, frag1b, 50, 2, 0, 1, 1, 50, 63, bid - 32, l);
    else if (bid < 384)
        prep_frag_body(W2ihF, W2hhF, b2F, frag2f, 150, 8, 0, 100, 100, 150, 255, bid - 64, l);
    else {
        int idx = (bid - 384) * 64 + l;          // WtT[k][g] = W2ihB[g][k]  (UNscaled)
        if (idx < 60000) {
            int k = idx / 600, g = idx - k * 600;
            WtT[idx] = W2ihB[g * 100 + k];
        }
    }
}

// ---------------------------------------------------------------------------
// Layer 1: K=64 (x k=0, h k=1..50, bias k=63). 512 thr = 8 waves, 2 tiles per
// wave (tile = w, w+8; tiles 13..15 zero), jj = tile*4 + q (< 50).
// out1f layout: u16 fragment tensor [t][blk16][ktx(4)][lane(64)][e(8)].
__global__ __launch_bounds__(512, 2) void l1_scan(
    const float* __restrict__ x, const uint4* __restrict__ fragF,
    const uint4* __restrict__ fragB, u16* __restrict__ out1f)
{
    const int tid = threadIdx.x;
    const int lane = tid & 63;
    const int w = tid >> 6;           // 0..7
    const int q = lane >> 4;
    const int b = lane & 15;
    const int blk = blockIdx.x;
    const int dir = blockIdx.y;
    const uint4* frag = dir ? fragB : fragF;

    __shared__ u16 v[2][1024];        // [buf][kt(2)*64 lanes*8 e]
    __shared__ float x_s[128][17];    // padded: conflict-free col reads

    uint4 af[2][2];
    #pragma unroll
    for (int p = 0; p < 2; ++p)
        #pragma unroll
        for (int kt = 0; kt < 2; ++kt)
            af[p][kt] = frag[((w + 8 * p) * 2 + kt) * 64 + lane];

    const int b0 = blk * 16;
    for (int idx = tid; idx < 1024; idx += 512) ((u32*)v)[idx] = 0u;
    for (int idx = tid; idx < 2048; idx += 512) {
        int bb = idx >> 7, t = idx & 127;
        x_s[t][bb] = x[(size_t)(b0 + bb) * TT + t];
    }
    __syncthreads();                  // zero-init complete before special slots
    const u16 oneh = to_h(1.0f);
    if (tid < 16) {
        v[0][(112 + tid) * 8 + 7] = oneh;             // bias row k=63, both bufs
        v[1][(112 + tid) * 8 + 7] = oneh;
        v[0][tid * 8] = to_h(x[(size_t)(b0 + tid) * TT + (dir ? TT - 1 : 0)]);
    }
    int vslot[2]; size_t eb[2];
    #pragma unroll
    for (int p = 0; p < 2; ++p) {
        int jj = (w + 8 * p) * 4 + q;
        int k1 = 1 + (jj < 50 ? jj : 0);
        vslot[p] = ((k1 >> 5) * 64 + ((k1 & 31) >> 3) * 16 + b) * 8 + (k1 & 7);
        int k2 = dir * 50 + (jj < 50 ? jj : 0);
        eb[p] = (((size_t)blk * 4 + (k2 >> 5)) * 64
                 + ((k2 & 31) >> 3) * 16 + b) * 8 + (k2 & 7);
    }
    float c[2] = {0.f, 0.f};
    __syncthreads();

#define L1_STEP(T, CUR) { \
    uint4 bf0 = *(const uint4*)&v[CUR][lane * 8]; \
    uint4 bf1 = *(const uint4*)&v[CUR][(64 + lane) * 8]; \
    f32x4 acc[2]; \
    _Pragma("unroll") for (int p = 0; p < 2; ++p) { \
        acc[p] = mfma16(af[p][0], bf0, (f32x4){0.f, 0.f, 0.f, 0.f}); \
        acc[p] = mfma16(af[p][1], bf1, acc[p]); \
    } \
    const int tt = dir ? 127 - (T) : (T); \
    _Pragma("unroll") for (int p = 0; p < 2; ++p) { \
        int jj = (w + 8 * p) * 4 + q; \
        if (jj < 50) { \
            float hn = lstm_cell(acc[p][0], acc[p][1], acc[p][2], acc[p][3], c[p]); \
            u16 hb = to_h(hn); \
            out1f[eb[p] + (size_t)tt * 131072] = hb; \
            v[1 - (CUR)][vslot[p]] = hb; \
        } \
    } \
    if (tid < 16 && (T) < 127) \
        v[1 - (CUR)][tid * 8] = to_h(x_s[dir ? 126 - (T) : (T) + 1][tid]); \
    wg_barrier_lds(); }

    for (int t2 = 0; t2 < TT; t2 += 2) {
        L1_STEP(t2, 0)
        L1_STEP(t2 + 1, 1)
    }
#undef L1_STEP
}

// ---------------------------------------------------------------------------
// Layer 2 forward: K=256 (x k=0..99, h k=100..249, bias k=255). 512 thr = 8
// waves, 5 tiles/wave (tile = w + 8p), jj = tile*4 + q (< 150).
// Step: ds_read bfu; 25 h-MFMAs into ACCC (holds x(t) part); refill pf with
// x(t+2) via loop-carried pointer; then ONE region with cells(ACCC) and the
// 15 x-MFMAs(t+1)->ACCN so VALU/trans overlaps the MFMA pipe. 1 barrier/step.
__global__ __launch_bounds__(512, 2) void l2f_scan(
    const uint4* __restrict__ frag, const u16* __restrict__ out1f,
    float* __restrict__ net)
{
    const int tid = threadIdx.x;
    const int lane = tid & 63;
    const int w = tid >> 6;           // 0..7
    const int q = lane >> 4;
    const int b = lane & 15;
    const int blk = blockIdx.x;
    const int b0 = blk * 16;
    const uint4* o4 = (const uint4*)out1f;

    __shared__ u16 v[2][4096];        // [buf][kt(8)*64 lanes*8 e]

    uint4 af[5][8];
    #pragma unroll
    for (int i = 0; i < 5; ++i)
        #pragma unroll
        for (int kt = 0; kt < 8; ++kt)
            af[i][kt] = frag[((w + 8 * i) * 8 + kt) * 64 + lane];

    for (int idx = tid; idx < 4096; idx += 512) ((u32*)v)[idx] = 0u;

    // Loop-carried prefetch pointer: x(t) frags at o4 + t*16384 + blk*256 + lane,
    // ktx at immediate offset ktx*64 uint4 (1024 B — fits the 13-bit signed imm).
    const uint4* pfp = o4 + (size_t)blk * 256 + lane;
    uint4 pfA[4], pfB[4];
    #pragma unroll
    for (int ktx = 0; ktx < 4; ++ktx) pfA[ktx] = pfp[ktx * 64];   // x(0)
    pfp += 16384;
    #pragma unroll
    for (int ktx = 0; ktx < 4; ++ktx) pfB[ktx] = pfp[ktx * 64];   // x(1)
    pfp += 16384;                                                  // -> x(2)

    __syncthreads();                  // zero-init complete before special slots
    const u16 oneh = to_h(1.0f);
    if (tid < 16) {                   // bias row k=255, both bufs
        v[0][(496 + tid) * 8 + 7] = oneh;
        v[1][(496 + tid) * 8 + 7] = oneh;
    }
    if (w == 0 && lane < 16) {        // x(0) k=96..99 into v[0] kt3 slots
        uint2 xv; xv.x = pfA[3].x; xv.y = pfA[3].y;
        *(uint2*)&v[0][(192 + lane) * 8] = xv;
    }

    int vslot[5];
    #pragma unroll
    for (int p = 0; p < 5; ++p) {
        int jj = (w + 8 * p) * 4 + q;
        int k = 100 + (jj < 150 ? jj : 0);
        vslot[p] = ((k >> 5) * 64 + ((k & 31) >> 3) * 16 + b) * 8 + (k & 7);
    }
    float c[5] = {0.f, 0.f, 0.f, 0.f, 0.f};

    // Prologue: accA = x-part(0) from pfA (kt0..2; x k=96..99 comes via LDS).
    f32x4 accA[5], accB[5];
    #pragma unroll
    for (int p = 0; p < 5; ++p) {
        accA[p] = mfma16(af[p][0], pfA[0], (f32x4){0.f, 0.f, 0.f, 0.f});
        accA[p] = mfma16(af[p][1], pfA[1], accA[p]);
        accA[p] = mfma16(af[p][2], pfA[2], accA[p]);
    }
    __syncthreads();

// Step T: ACCC holds x(T)-part; PFOTH holds x(T+1); PFREF refilled with x(T+2).
#define L2F_STEP(T, CUR, ACCC, ACCN, PFREF, PFOTH) { \
    uint4 bfu[5]; \
    _Pragma("unroll") for (int kh = 0; kh < 5; ++kh) \
        bfu[kh] = *(const uint4*)&v[CUR][((kh + 3) * 64 + lane) * 8]; \
    _Pragma("unroll") for (int kh = 0; kh < 5; ++kh) { \
        _Pragma("unroll") for (int p = 0; p < 5; ++p) \
            ACCC[p] = mfma16(af[p][kh + 3], bfu[kh], ACCC[p]); \
    } \
    _Pragma("unroll") for (int ktx = 0; ktx < 4; ++ktx) \
        PFREF[ktx] = pfp[ktx * 64]; \
    pfp += 16384; \
    _Pragma("unroll") for (int p = 0; p < 5; ++p) { \
        ACCN[p] = mfma16(af[p][0], PFOTH[0], (f32x4){0.f, 0.f, 0.f, 0.f}); \
        ACCN[p] = mfma16(af[p][1], PFOTH[1], ACCN[p]); \
        ACCN[p] = mfma16(af[p][2], PFOTH[2], ACCN[p]); \
        int jj = (w + 8 * p) * 4 + q; \
        if (jj < 150) { \
            float hn = lstm_cell(ACCC[p][0], ACCC[p][1], ACCC[p][2], ACCC[p][3], c[p]); \
            v[1 - (CUR)][vslot[p]] = to_h(hn); \
            if ((T) == 127) net[(size_t)(b0 + b) * 300 + jj] = hn; \
        } \
    } \
    if (w == 0 && lane < 16) { \
        uint2 xv; xv.x = PFOTH[3].x; xv.y = PFOTH[3].y; \
        *(uint2*)&v[1 - (CUR)][(192 + lane) * 8] = xv; \
    } \
    wg_barrier_lds(); }

    for (int t2 = 0; t2 < TT; t2 += 2) {
        L2F_STEP(t2, 0, accA, accB, pfA, pfB)
        L2F_STEP(t2 + 1, 1, accB, accA, pfB, pfA)
    }
#undef L2F_STEP
    // (tail reads of x(128)/x(129) land inside ws (net region) — harmless,
    //  values feed an acc that is never consumed.)
}

// ---------------------------------------------------------------------------
// Layer 2 backward = single step from zero state (Whh_b drops out).
__global__ __launch_bounds__(640, 1) void l2b_step(
    const u16* __restrict__ out1f, const float* __restrict__ WtT,
    const float* __restrict__ bias, float* __restrict__ net)   // writes [:, 150:300]
{
    const int tid = threadIdx.x;
    const int blk = blockIdx.x;
    const int b0 = blk * 16;
    __shared__ alignas(16) float x_s[100][16];
    __shared__ alignas(16) float gbuf[16][644];
    for (int idx = tid; idx < 1600; idx += 640) {
        int k2 = idx >> 4, bb = idx & 15;
        x_s[k2][bb] = from_h(out1f[((((size_t)127 * 64 + blk) * 4 + (k2 >> 5)) * 64
                                    + ((k2 & 31) >> 3) * 16 + bb) * 8 + (k2 & 7)]);
    }
    __syncthreads();
    if (tid < 600) {
        int g = tid;
        float acc[16];
        #pragma unroll
        for (int bb = 0; bb < 16; ++bb) acc[bb] = 0.f;
        for (int k = 0; k < 100; ++k) {
            float wv = WtT[k * 600 + g];
            float4 xa = *(const float4*)&x_s[k][0];
            float4 xb = *(const float4*)&x_s[k][4];
            float4 xc = *(const float4*)&x_s[k][8];
            float4 xd = *(const float4*)&x_s[k][12];
            acc[0] = fmaf(wv, xa.x, acc[0]);  acc[1] = fmaf(wv, xa.y, acc[1]);
            acc[2] = fmaf(wv, xa.z, acc[2]);  acc[3] = fmaf(wv, xa.w, acc[3]);
            acc[4] = fmaf(wv, xb.x, acc[4]);  acc[5] = fmaf(wv, xb.y, acc[5]);
            acc[6] = fmaf(wv, xb.z, acc[6]);  acc[7] = fmaf(wv, xb.w, acc[7]);
            acc[8] = fmaf(wv, xc.x, acc[8]);  acc[9] = fmaf(wv, xc.y, acc[9]);
            acc[10] = fmaf(wv, xc.z, acc[10]); acc[11] = fmaf(wv, xc.w, acc[11]);
            acc[12] = fmaf(wv, xd.x, acc[12]); acc[13] = fmaf(wv, xd.y, acc[13]);
            acc[14] = fmaf(wv, xd.z, acc[14]); acc[15] = fmaf(wv, xd.w, acc[15]);
        }
        #pragma unroll
        for (int bb = 0; bb < 16; ++bb) gbuf[bb][g] = acc[bb];
    }
    __syncthreads();
    for (int idx = tid; idx < 2400; idx += 640) {
        int j = idx >> 4, bb = idx & 15;
        float ig = gbuf[bb][j]       + bias[j];
        float gg = gbuf[bb][j + 300] + bias[j + 300];
        float og = gbuf[bb][j + 450] + bias[j + 450];
        float cn = sigm(ig) * tanh_(gg);           // c0 = 0 -> forget term vanishes
        float hn = sigm(og) * tanh_(cn);
        net[(size_t)(b0 + bb) * 300 + 150 + j] = hn;
    }
}

// waveform_feat + pef + pef_logits + feat
__global__ void head1(const float* __restrict__ net, const float* __restrict__ rrs,
                      const float* __restrict__ headW, const float* __restrict__ headb,
                      const float* __restrict__ p1W, const float* __restrict__ p1b,
                      const float* __restrict__ p2W, const float* __restrict__ p2b,
                      float* __restrict__ out)
{
    int gid = blockIdx.x * 256 + threadIdx.x;     // 4096
    int b = gid >> 2, og = gid & 3;
    float acc[5];
    #pragma unroll
    for (int o2 = 0; o2 < 5; ++o2) acc[o2] = headb[og * 5 + o2];
    const float* nb = net + (size_t)b * 300;
    for (int k = 0; k < 300; ++k) {
        float nv = nb[k];
        #pragma unroll
        for (int o2 = 0; o2 < 5; ++o2)
            acc[o2] = fmaf(headW[(og * 5 + o2) * 300 + k], nv, acc[o2]);
    }
    #pragma unroll
    for (int o2 = 0; o2 < 5; ++o2) {
        int o = og * 5 + o2;
        float vv = acc[o2] > 0.f ? acc[o2] : 0.3f * acc[o2];
        out[b * 20 + o] = vv;                  // waveform_feat
        out[22528 + b * 30 + o] = vv;          // feat[:, :20]
    }
    if (og == 0) {
        float p[10];
        #pragma unroll
        for (int r = 0; r < 10; ++r) {
            float a = p1b[r];
            #pragma unroll
            for (int qq = 0; qq < 4; ++qq) a = fmaf(p1W[r * 4 + qq], rrs[b * 4 + qq], a);
            p[r] = a > 0.f ? a : 0.3f * a;
            out[22528 + b * 30 + 20 + r] = p[r];   // feat[:, 20:30]
        }
        #pragma unroll
        for (int s = 0; s < 2; ++s) {
            float a = p2b[s];
            #pragma unroll
            for (int r = 0; r < 10; ++r) a = fmaf(p2W[s * 10 + r], p[r], a);
            out[20480 + b * 2 + s] = a;            // pef_logits
        }
    }
}

__global__ void head2(const float* __restrict__ fcW, const float* __restrict__ fcb,
                      float* __restrict__ out)
{
    int b = blockIdx.x * 256 + threadIdx.x;   // 1024
    const float* feat = out + 22528 + b * 30;
    float f[30];
    #pragma unroll
    for (int k = 0; k < 30; ++k) f[k] = feat[k];
    #pragma unroll
    for (int s = 0; s < 4; ++s) {
        float a = fcb[s];
        #pragma unroll
        for (int k = 0; k < 30; ++k) a = fmaf(fcW[s * 30 + k], f[k], a);
        out[53248 + b * 4 + s] = a;
    }
}

extern "C" void kernel_launch(void* const* d_in, const int* in_sizes, int n_in,
                              void* d_out, int out_size, void* d_ws, size_t ws_size,
                              hipStream_t stream)
{
    const float* x     = (const float*)d_in[0];
    const float* rrs   = (const float*)d_in[1];
    const float* W1ihF = (const float*)d_in[2];
    const float* W1hhF = (const float*)d_in[3];
    const float* b1F   = (const float*)d_in[4];
    const float* W1ihB = (const float*)d_in[5];
    const float* W1hhB = (const float*)d_in[6];
    const float* b1B   = (const float*)d_in[7];
    const float* W2ihF = (const float*)d_in[8];
    const float* W2hhF = (const float*)d_in[9];
    const float* b2F   = (const float*)d_in[10];
    const float* W2ihB = (const float*)d_in[11];
    // d_in[12] (l2_Whh_b) unused: backward output at t=T-1 starts from h0=0.
    const float* b2B   = (const float*)d_in[13];
    const float* headW = (const float*)d_in[14];
    const float* headb = (const float*)d_in[15];
    const float* p1W   = (const float*)d_in[16];
    const float* p1b   = (const float*)d_in[17];
    const float* p2W   = (const float*)d_in[18];
    const float* p2b   = (const float*)d_in[19];
    const float* fcW   = (const float*)d_in[20];
    const float* fcb   = (const float*)d_in[21];
    float* out = (float*)d_out;

    char* ws = (char*)d_ws;
    uint4* frag1f = (uint4*)(ws + 0);          //  32 KB (16 tiles x 2 kt)
    uint4* frag1b = (uint4*)(ws + 32768);      //  32 KB
    uint4* frag2f = (uint4*)(ws + 65536);      // 320 KB (40 tiles x 8 kt)
    float* WtT    = (float*)(ws + 393216);     // 240 KB (Wih2_b^T [100][600])
    u16*   out1f  = (u16*)(ws + 655360);       //  32 MB ([128][64][4][64][8] u16)
    float* net    = (float*)(ws + 655360 + 33554432);  // 1.2 MB ([1024][300])
    (void)ws_size; (void)in_sizes; (void)n_in; (void)out_size;

    prep_all<<<1322, 64, 0, stream>>>(W1ihF, W1hhF, b1F, W1ihB, W1hhB, b1B,
                                      W2ihF, W2hhF, b2F, W2ihB,
                                      frag1f, frag1b, frag2f, WtT);
    l1_scan<<<dim3(64, 2), 512, 0, stream>>>(x, frag1f, frag1b, out1f);
    l2f_scan<<<64, 512, 0, stream>>>(frag2f, out1f, net);
    l2b_step<<<64, 640, 0, stream>>>(out1f, WtT, b2B, net);
    head1<<<16, 256, 0, stream>>>(net, rrs, headW, headb, p1W, p1b, p2W, p2b, out);
    head2<<<4, 256, 0, stream>>>(fcW, fcb, out);
}